// Round 13
// baseline (310.680 us; speedup 1.0000x reference)
//
#include <hip/hip_runtime.h>
#include <hip/hip_bf16.h>
#include <math.h>

#define D 128
#define LRELU_SLOPE 0.2f
#define BSH 9
#define BSZ 512
#define BCAP 10240
#define SC_CHUNK 16384

typedef __attribute__((ext_vector_type(8))) short bf16x8;
typedef __attribute__((ext_vector_type(4))) float f32x4;

__device__ __forceinline__ float lrelu(float x){ return x > 0.f ? x : LRELU_SLOPE * x; }

__device__ __forceinline__ unsigned short bf16_rn(float x){
  unsigned int u = __float_as_uint(x);
  return (unsigned short)((u + 0x7FFFu + ((u >> 16) & 1u)) >> 16);
}
__device__ __forceinline__ float bf16_lo_f(unsigned int u){ return __uint_as_float(u << 16); }
__device__ __forceinline__ float bf16_hi_f(unsigned int u){ return __uint_as_float(u & 0xFFFF0000u); }

__device__ __forceinline__ unsigned int enc_f(float f){
  unsigned int u = __float_as_uint(f);
  return (u & 0x80000000u) ? ~u : (u | 0x80000000u);
}
__device__ __forceinline__ float dec_f(unsigned int e){
  return __uint_as_float((e & 0x80000000u) ? (e & 0x7FFFFFFFu) : ~e);
}

// permuted position p -> actual column
__device__ __forceinline__ int colmap(int p){ return ((p & 7) << 4) + (p >> 3); }

// ---------------- edge scatter into fixed-stride buckets ----------------
__global__ __launch_bounds__(1024) void bucket_scatter_kernel(const int* __restrict__ src,
    const int* __restrict__ dst, int E, int* __restrict__ bcur,
    unsigned int* __restrict__ ebuf, int nbuck){
  __shared__ int h[256];
  __shared__ int cb[256];
  int t = threadIdx.x;
  int base = blockIdx.x * SC_CHUNK;
  int end = base + SC_CHUNK; if (end > E) end = E;
  if (t < 256) h[t] = 0;
  __syncthreads();
  for (int e = base + t; e < end; e += 1024)
    atomicAdd(&h[dst[e] >> BSH], 1);
  __syncthreads();
  if (t < nbuck){
    cb[t] = h[t] ? atomicAdd(&bcur[t], h[t]) : 0;
    h[t] = 0;
  }
  __syncthreads();
  for (int e = base + t; e < end; e += 1024){
    int d = dst[e];
    int b = d >> BSH;
    int lpos = atomicAdd(&h[b], 1);
    ebuf[cb[b] + lpos] = ((unsigned int)src[e] << BSH) | (unsigned int)(d & (BSZ-1));
  }
}

__global__ __launch_bounds__(256) void bucket_csr_kernel(const unsigned int* __restrict__ ebuf,
    const int* __restrict__ bcur, int2* __restrict__ rowrange, int* __restrict__ colb,
    int n, int nbuck){
  __shared__ int c[512];
  __shared__ int ps[256];
  int b = blockIdx.x;
  int t = threadIdx.x;
  int base = b * BCAP;
  int end  = bcur[b];
  c[t] = 0; c[t+256] = 0;
  __syncthreads();
  for (int i = base + t; i < end; i += 256)
    atomicAdd(&c[ebuf[i] & (BSZ-1)], 1);
  __syncthreads();
  int a0 = c[2*t], a1 = c[2*t+1];
  int pair = a0 + a1;
  ps[t] = pair;
  __syncthreads();
  #pragma unroll
  for (int d = 1; d < 256; d <<= 1){
    int add = (t >= d) ? ps[t-d] : 0;
    __syncthreads();
    ps[t] += add;
    __syncthreads();
  }
  int excl = ps[t] - pair;
  __syncthreads();
  int lo = b << BSH;
  int g0 = lo + 2*t, g1 = g0 + 1;
  if (g0 < n) rowrange[g0] = make_int2(base + excl,      base + excl + a0);
  if (g1 < n) rowrange[g1] = make_int2(base + excl + a0, base + excl + a0 + a1);
  c[2*t]   = excl;
  c[2*t+1] = excl + a0;
  __syncthreads();
  for (int i = base + t; i < end; i += 256){
    unsigned int p = ebuf[i];
    int dlo = p & (BSZ-1);
    int pos = base + atomicAdd(&c[dlo], 1);
    colb[pos] = (int)(p >> BSH);
  }
}

// ---------------- W pre-split (layer 2 gets k-permuted fragments) ----------------
__global__ __launch_bounds__(256) void wsplit_kernel(const float* __restrict__ W1,
    const float* __restrict__ W2,
    unsigned short* __restrict__ Whf1, unsigned short* __restrict__ Wlf1,
    unsigned short* __restrict__ Whf2, unsigned short* __restrict__ Wlf2){
  int b = blockIdx.x;
  bool layer2 = (b >= 64);
  const float* W = layer2 ? W2 : W1;
  unsigned short* Whf = layer2 ? Whf2 : Whf1;
  unsigned short* Wlf = layer2 ? Wlf2 : Wlf1;
  int t = (b & 63)*256 + threadIdx.x;   // 0..16383
  int k  = t >> 7;
  int nn = t & 127;
  float w = W[t];
  unsigned short h = bf16_rn(w);
  float whf = __uint_as_float(((unsigned int)h) << 16);
  unsigned short l = bf16_rn(w - whf);
  int ks = layer2 ? (((k & 15) << 3) + (k >> 4)) : k;   // col(ks) == k
  int kc = ks >> 5, l4 = (ks >> 3) & 3, e = ks & 7;
  int cf = nn >> 4, l15 = nn & 15;
  int idx = ((kc*8 + cf)*64 + l4*16 + l15)*8 + e;
  Whf[idx] = h; Wlf[idx] = l;
}

// ---------------- Wa dots + logit B-tile + permuted bias + init duties ----------------
__global__ __launch_bounds__(256) void wafrag_kernel(const float* __restrict__ W1,
    const float* __restrict__ W2,
    const float* __restrict__ as1, const float* __restrict__ ad1,
    const float* __restrict__ as2, const float* __restrict__ ad2,
    const float* __restrict__ b1,
    unsigned short* __restrict__ Whfx1, unsigned short* __restrict__ Wlfx1,
    unsigned short* __restrict__ Whfx2, unsigned short* __restrict__ Wlfx2,
    float* __restrict__ bias_perm1,
    unsigned int* __restrict__ mx, int* __restrict__ bcur, int nbuck){
  __shared__ float wa[2][128];
  int layer = blockIdx.x;
  const float* W  = layer ? W2 : W1;
  const float* as = layer ? as2 : as1;
  const float* ad = layer ? ad2 : ad1;
  unsigned short* Whfx = layer ? Whfx2 : Whfx1;
  unsigned short* Wlfx = layer ? Wlfx2 : Wlfx1;
  int t = threadIdx.x;
  if (t < 2) mx[layer*2 + t] = 0u;
  if (layer == 0 && t < nbuck) bcur[t] = t * BCAP;
  if (layer == 0 && t < 128) bias_perm1[t] = b1[colmap(t)];

  int row = t & 127;
  const float* a = (t >> 7) ? ad : as;
  float s = 0.f;
  #pragma unroll 8
  for (int c = 0; c < 128; c += 4){
    float4 wv = *(const float4*)&W[row*128 + c];
    s += wv.x*a[c] + wv.y*a[c+1] + wv.z*a[c+2] + wv.w*a[c+3];
  }
  wa[t >> 7][row] = s;
  __syncthreads();

  int kc = t >> 6, lane = t & 63;
  int l15 = lane & 15, l4 = lane >> 4;
  unsigned short hh[8], ll[8];
  #pragma unroll
  for (int e = 0; e < 8; ++e){
    int ks = (kc*4 + l4)*8 + e;                 // stored slot
    int k  = layer ? colmap(ks) : ks;           // actual k this slot must hold
    float v = (l15 == 0) ? wa[0][k] : ((l15 == 1) ? wa[1][k] : 0.f);
    unsigned short h = bf16_rn(v);
    hh[e] = h;
    ll[e] = bf16_rn(v - __uint_as_float(((unsigned)h) << 16));
  }
  #pragma unroll
  for (int e = 0; e < 8; ++e){ Whfx[t*8 + e] = hh[e]; Wlfx[t*8 + e] = ll[e]; }
}

// ---------------- MFMA bf16 GEMM (2-term) + MFMA logits, 64-row tile ----------------
// Hb stored in PERMUTED row layout: ushort p of row r holds H[r][colmap(p)].
// BF16IN: X is bf16 rows already in permuted order (k-permuted W fragments match).
template<bool BF16IN>
__global__ __launch_bounds__(256) void gemm_al_kernel(const void* __restrict__ Xv,
    const unsigned short* __restrict__ Whf, const unsigned short* __restrict__ Wlf,
    const unsigned short* __restrict__ Whfx, const unsigned short* __restrict__ Wlfx,
    unsigned short* __restrict__ Hb, float* __restrict__ ALs, float* __restrict__ ALd,
    unsigned int* __restrict__ mx, int n)
{
  __shared__ unsigned short Xh[64*128];   // 16 KB
  __shared__ float redS[4], redD[4];
  int tid  = threadIdx.x;
  int lane = tid & 63;
  int wave = tid >> 6;
  int row0 = blockIdx.x * 64;

  if constexpr (BF16IN){
    const uint4* X4 = (const uint4*)Xv;
    #pragma unroll
    for (int it = 0; it < 4; ++it){
      int f  = it*256 + tid;      // 0..1023
      int r  = f >> 4;            // 0..63
      int pg = f & 15;            // 16B group within row
      uint4 v = make_uint4(0u,0u,0u,0u);
      int gr = row0 + r;
      if (gr < n) v = X4[(size_t)gr*16 + pg];
      *(uint4*)&Xh[r*128 + ((pg ^ (r & 7)) << 3)] = v;
    }
  } else {
    const float* X = (const float*)Xv;
    #pragma unroll 4
    for (int it = 0; it < 8; ++it){
      int f  = it*256 + tid;      // 0..2047
      int r  = f >> 5;            // 0..63
      int c4 = f & 31;
      float4 v = make_float4(0.f,0.f,0.f,0.f);
      int gr = row0 + r;
      if (gr < n) v = ((const float4*)(X + (size_t)gr*D))[c4];
      unsigned short h0 = bf16_rn(v.x);
      unsigned short h1 = bf16_rn(v.y);
      unsigned short h2 = bf16_rn(v.z);
      unsigned short h3 = bf16_rn(v.w);
      int g   = (c4 >> 1) ^ (r & 7);
      int idx = r*128 + (g << 3) + ((c4 & 1) << 2);
      *(uint2*)&Xh[idx] = make_uint2((unsigned)h0 | ((unsigned)h1<<16),
                                     (unsigned)h2 | ((unsigned)h3<<16));
    }
  }
  __syncthreads();

  int l15 = lane & 15;
  int l4  = lane >> 4;

  f32x4 acc[8];
  f32x4 acc2;
  #pragma unroll
  for (int cf = 0; cf < 8; ++cf) acc[cf] = (f32x4){0.f, 0.f, 0.f, 0.f};
  acc2 = (f32x4){0.f, 0.f, 0.f, 0.f};

  #pragma unroll
  for (int kc = 0; kc < 4; ++kc){
    int g = kc*4 + l4;
    int r = wave*16 + l15;
    bf16x8 ah = *(const bf16x8*)&Xh[r*128 + ((g ^ (r & 7)) << 3)];
    #pragma unroll
    for (int cf = 0; cf < 8; ++cf){
      int foff = ((kc*8 + cf) << 9) + (lane << 3);
      bf16x8 bh = *(const bf16x8*)&Whf[foff];
      bf16x8 bl = *(const bf16x8*)&Wlf[foff];
      acc[cf] = __builtin_amdgcn_mfma_f32_16x16x32_bf16(ah, bh, acc[cf], 0, 0, 0);
      acc[cf] = __builtin_amdgcn_mfma_f32_16x16x32_bf16(ah, bl, acc[cf], 0, 0, 0);
    }
    {
      int foffx = ((kc << 6) + lane) << 3;
      bf16x8 bhx = *(const bf16x8*)&Whfx[foffx];
      bf16x8 blx = *(const bf16x8*)&Wlfx[foffx];
      acc2 = __builtin_amdgcn_mfma_f32_16x16x32_bf16(ah, bhx, acc2, 0, 0, 0);
      acc2 = __builtin_amdgcn_mfma_f32_16x16x32_bf16(ah, blx, acc2, 0, 0, 0);
    }
  }

  float ms = -3e38f, md = -3e38f;
  #pragma unroll
  for (int reg = 0; reg < 4; ++reg){
    int gr = row0 + wave*16 + l4*4 + reg;   // C/D: row=(lane>>4)*4+reg
    if (gr < n){
      unsigned int p0 = (unsigned)bf16_rn(acc[0][reg]) | ((unsigned)bf16_rn(acc[1][reg]) << 16);
      unsigned int p1 = (unsigned)bf16_rn(acc[2][reg]) | ((unsigned)bf16_rn(acc[3][reg]) << 16);
      unsigned int p2 = (unsigned)bf16_rn(acc[4][reg]) | ((unsigned)bf16_rn(acc[5][reg]) << 16);
      unsigned int p3 = (unsigned)bf16_rn(acc[6][reg]) | ((unsigned)bf16_rn(acc[7][reg]) << 16);
      ((uint4*)(Hb + (size_t)gr*D))[l15] = make_uint4(p0, p1, p2, p3);
      if (l15 == 0){      ALs[gr] = acc2[reg]; ms = fmaxf(ms, acc2[reg]); }
      else if (l15 == 1){ ALd[gr] = acc2[reg]; md = fmaxf(md, acc2[reg]); }
    }
  }
  // block-level max reduce -> one atomic pair per block
  #pragma unroll
  for (int off = 32; off >= 1; off >>= 1){
    ms = fmaxf(ms, __shfl_xor(ms, off));
    md = fmaxf(md, __shfl_xor(md, off));
  }
  if (lane == 0){ redS[wave] = ms; redD[wave] = md; }
  __syncthreads();
  if (tid == 0){
    float a = fmaxf(fmaxf(redS[0], redS[1]), fmaxf(redS[2], redS[3]));
    float b = fmaxf(fmaxf(redD[0], redD[1]), fmaxf(redD[2], redD[3]));
    atomicMax(&mx[0], enc_f(a));
    atomicMax(&mx[1], enc_f(b));
  }
}

// ---------------- fused softmax + weighted gather aggregation ----------------
// BF16OUT: write bf16 permuted rows (layer-1 handoff; bias pre-permuted).
// else: un-permute via shuffles and write fp32 (final output).
template<bool BF16OUT>
__global__ __launch_bounds__(256) void agg_kernel(const unsigned short* __restrict__ Hb,
    const float* __restrict__ ALs, const float* __restrict__ ALd,
    const unsigned int* __restrict__ mx,
    const int2* __restrict__ rowrange, const int* __restrict__ colb,
    const float* __restrict__ bias, void* __restrict__ outv, int n)
{
  __shared__ unsigned int sArr[256];
  __shared__ float wArr[256];
  int gtid = blockIdx.x*blockDim.x + threadIdx.x;
  int node = gtid >> 6;
  int lane = threadIdx.x & 63;
  int wbase = threadIdx.x & 192;
  if (node >= n) return;

  float M = lrelu(dec_f(mx[0]) + dec_f(mx[1]));

  int2 rr = rowrange[node];
  int beg = rr.x, end = rr.y;
  float ald = ALd[node];
  float ws = __expf(lrelu(ALs[node] + ald) - M);

  const unsigned int* H2 = (const unsigned int*)Hb;
  unsigned int us = H2[(unsigned)(node*64 + lane)];
  float2 acc; acc.x = ws * bf16_lo_f(us); acc.y = ws * bf16_hi_f(us);
  float zl = 0.f;

  for (int c = beg; c < end; c += 64){
    int j = c + lane;
    bool valid = j < end;
    int s_l = valid ? colb[j] : 0;
    float w_l = valid ? __expf(lrelu(ALs[s_l] + ald) - M) : 0.f;
    zl += w_l;

    sArr[threadIdx.x] = (unsigned)s_l;
    wArr[threadIdx.x] = w_l;

    int cnt = end - c; if (cnt > 64) cnt = 64;
    int q = 0;
    for (; q + 8 <= cnt; q += 8){
      unsigned int ss[8]; float ww[8]; unsigned int u[8];
      #pragma unroll
      for (int p = 0; p < 8; ++p){ ss[p] = sArr[wbase + q + p]; ww[p] = wArr[wbase + q + p]; }
      #pragma unroll
      for (int p = 0; p < 8; ++p) u[p] = H2[(unsigned)(ss[p]*64u + lane)];
      #pragma unroll
      for (int p = 0; p < 8; ++p){
        acc.x += ww[p]*bf16_lo_f(u[p]);
        acc.y += ww[p]*bf16_hi_f(u[p]);
      }
    }
    for (; q < cnt; ++q){
      unsigned int u = H2[(unsigned)(sArr[wbase + q]*64u + lane)];
      float w = wArr[wbase + q];
      acc.x += w*bf16_lo_f(u); acc.y += w*bf16_hi_f(u);
    }
  }

  #pragma unroll
  for (int off = 32; off >= 1; off >>= 1) zl += __shfl_xor(zl, off);
  float zi = 1.f / (zl + ws);
  acc.x *= zi; acc.y *= zi;

  if constexpr (BF16OUT){
    // stay in permuted layout; bias is pre-permuted
    float2 bp = ((const float2*)bias)[lane];
    unsigned int w = (unsigned)bf16_rn(acc.x + bp.x) | ((unsigned)bf16_rn(acc.y + bp.y) << 16);
    ((unsigned int*)outv)[(unsigned)(node*64 + lane)] = w;
  } else {
    // permuted -> standard: lane t needs cols 2t (v0) and 2t+1 (v1)
    int q0 = (lane >> 4) + ((lane & 7) << 3);
    int q1 = q0 + 4;
    int hsel = (lane >> 3) & 1;
    float x0 = __shfl(acc.x, q0), y0 = __shfl(acc.y, q0);
    float x1 = __shfl(acc.x, q1), y1 = __shfl(acc.y, q1);
    float v0 = hsel ? y0 : x0;
    float v1 = hsel ? y1 : x1;
    float2 b2 = ((const float2*)bias)[lane];
    ((float2*)outv)[(size_t)node*64 + lane] = make_float2(v0 + b2.x, v1 + b2.y);
  }
}

// ---------------- launch ----------------
extern "C" void kernel_launch(void* const* d_in, const int* in_sizes, int n_in,
                              void* d_out, int out_size, void* d_ws, size_t ws_size,
                              hipStream_t stream)
{
  const float* x   = (const float*)d_in[0];
  const int*   ei  = (const int*)  d_in[1];
  const float* W1  = (const float*)d_in[2];
  const float* as1 = (const float*)d_in[3];
  const float* ad1 = (const float*)d_in[4];
  const float* b1  = (const float*)d_in[5];
  const float* W2  = (const float*)d_in[6];
  const float* as2 = (const float*)d_in[7];
  const float* ad2 = (const float*)d_in[8];
  const float* b2  = (const float*)d_in[9];

  int n = in_sizes[0] / D;
  int E = in_sizes[1] / 2;
  const int* src = ei;
  const int* dst = ei + E;
  int nbuck = (n + BSZ - 1) >> BSH;

  char* base = (char*)d_ws;
  size_t off = 0;
  auto alloc = [&](size_t bytes) -> char* {
    char* p = base + off;
    off = (off + bytes + 255) & ~(size_t)255;
    return p;
  };
  unsigned short* hb  = (unsigned short*)alloc((size_t)n*D*2);
  unsigned short* hb2 = (unsigned short*)alloc((size_t)n*D*2);
  float* als    = (float*)alloc((size_t)n*4);
  float* ald    = (float*)alloc((size_t)n*4);
  int2* rowrange = (int2*)alloc((size_t)n*8);
  int* bcur     = (int*)alloc(256*4);
  unsigned int* mx = (unsigned int*)alloc(4*4);
  float* bias_perm1 = (float*)alloc(128*4);
  unsigned short* whf1 = (unsigned short*)alloc(16384*2);
  unsigned short* wlf1 = (unsigned short*)alloc(16384*2);
  unsigned short* whf2 = (unsigned short*)alloc(16384*2);
  unsigned short* wlf2 = (unsigned short*)alloc(16384*2);
  unsigned short* whfx1 = (unsigned short*)alloc(2048*2);
  unsigned short* wlfx1 = (unsigned short*)alloc(2048*2);
  unsigned short* whfx2 = (unsigned short*)alloc(2048*2);
  unsigned short* wlfx2 = (unsigned short*)alloc(2048*2);
  unsigned int* ebuf = (unsigned int*)alloc((size_t)nbuck*BCAP*4);
  int* colb = (int*)alloc((size_t)nbuck*BCAP*4);

  float* out = (float*)d_out;

  // prep: 2 dispatches
  wsplit_kernel<<<128, 256, 0, stream>>>(W1, W2, whf1, wlf1, whf2, wlf2);
  wafrag_kernel<<<2, 256, 0, stream>>>(W1, W2, as1, ad1, as2, ad2, b1,
                                       whfx1, wlfx1, whfx2, wlfx2,
                                       bias_perm1, mx, bcur, nbuck);

  // CSR build: 2 dispatches
  int sc_blocks = (E + SC_CHUNK - 1) / SC_CHUNK;
  bucket_scatter_kernel<<<sc_blocks, 1024, 0, stream>>>(src, dst, E, bcur, ebuf, nbuck);
  bucket_csr_kernel    <<<nbuck, 256, 0, stream>>>(ebuf, bcur, rowrange, colb, n, nbuck);

  int ntiles = (n + 63)/64;
  int aggblocks = (int)(((size_t)n*64 + 255)/256);

  gemm_al_kernel<false><<<ntiles, 256, 0, stream>>>(x,   whf1, wlf1, whfx1, wlfx1, hb, als, ald, mx,   n);
  agg_kernel<true>     <<<aggblocks, 256, 0, stream>>>(hb, als, ald, mx,   rowrange, colb, bias_perm1, hb2, n);
  gemm_al_kernel<true> <<<ntiles, 256, 0, stream>>>(hb2, whf2, wlf2, whfx2, wlfx2, hb, als, ald, mx+2, n);
  agg_kernel<false>    <<<aggblocks, 256, 0, stream>>>(hb, als, ald, mx+2, rowrange, colb, b2, out, n);
}

// Round 14
// 279.183 us; speedup vs baseline: 1.1128x; 1.1128x over previous
//
#include <hip/hip_runtime.h>
#include <hip/hip_bf16.h>
#include <math.h>

#define D 128
#define LRELU_SLOPE 0.2f
#define BSH 9
#define BSZ 512
#define BCAP 10240
#define SC_CHUNK 16384

typedef __attribute__((ext_vector_type(8))) short bf16x8;
typedef __attribute__((ext_vector_type(4))) float f32x4;

__device__ __forceinline__ float lrelu(float x){ return x > 0.f ? x : LRELU_SLOPE * x; }

__device__ __forceinline__ unsigned short bf16_rn(float x){
  unsigned int u = __float_as_uint(x);
  return (unsigned short)((u + 0x7FFFu + ((u >> 16) & 1u)) >> 16);
}
__device__ __forceinline__ float bf16_lo_f(unsigned int u){ return __uint_as_float(u << 16); }
__device__ __forceinline__ float bf16_hi_f(unsigned int u){ return __uint_as_float(u & 0xFFFF0000u); }

__device__ __forceinline__ unsigned int enc_f(float f){
  unsigned int u = __float_as_uint(f);
  return (u & 0x80000000u) ? ~u : (u | 0x80000000u);
}
__device__ __forceinline__ float dec_f(unsigned int e){
  return __uint_as_float((e & 0x80000000u) ? (e & 0x7FFFFFFFu) : ~e);
}

// permuted position p -> actual column
__device__ __forceinline__ int colmap(int p){ return ((p & 7) << 4) + (p >> 3); }

// ---------------- edge scatter into fixed-stride buckets ----------------
__global__ __launch_bounds__(1024) void bucket_scatter_kernel(const int* __restrict__ src,
    const int* __restrict__ dst, int E, int* __restrict__ bcur,
    unsigned int* __restrict__ ebuf, int nbuck){
  __shared__ int h[256];
  __shared__ int cb[256];
  int t = threadIdx.x;
  int base = blockIdx.x * SC_CHUNK;
  int end = base + SC_CHUNK; if (end > E) end = E;
  if (t < 256) h[t] = 0;
  __syncthreads();
  for (int e = base + t; e < end; e += 1024)
    atomicAdd(&h[dst[e] >> BSH], 1);
  __syncthreads();
  if (t < nbuck){
    cb[t] = h[t] ? atomicAdd(&bcur[t], h[t]) : 0;
    h[t] = 0;
  }
  __syncthreads();
  for (int e = base + t; e < end; e += 1024){
    int d = dst[e];
    int b = d >> BSH;
    int lpos = atomicAdd(&h[b], 1);
    ebuf[cb[b] + lpos] = ((unsigned int)src[e] << BSH) | (unsigned int)(d & (BSZ-1));
  }
}

__global__ __launch_bounds__(256) void bucket_csr_kernel(const unsigned int* __restrict__ ebuf,
    const int* __restrict__ bcur, int2* __restrict__ rowrange, int* __restrict__ colb,
    int n, int nbuck){
  __shared__ int c[512];
  __shared__ int ps[256];
  int b = blockIdx.x;
  int t = threadIdx.x;
  int base = b * BCAP;
  int end  = bcur[b];
  c[t] = 0; c[t+256] = 0;
  __syncthreads();
  for (int i = base + t; i < end; i += 256)
    atomicAdd(&c[ebuf[i] & (BSZ-1)], 1);
  __syncthreads();
  int a0 = c[2*t], a1 = c[2*t+1];
  int pair = a0 + a1;
  ps[t] = pair;
  __syncthreads();
  #pragma unroll
  for (int d = 1; d < 256; d <<= 1){
    int add = (t >= d) ? ps[t-d] : 0;
    __syncthreads();
    ps[t] += add;
    __syncthreads();
  }
  int excl = ps[t] - pair;
  __syncthreads();
  int lo = b << BSH;
  int g0 = lo + 2*t, g1 = g0 + 1;
  if (g0 < n) rowrange[g0] = make_int2(base + excl,      base + excl + a0);
  if (g1 < n) rowrange[g1] = make_int2(base + excl + a0, base + excl + a0 + a1);
  c[2*t]   = excl;
  c[2*t+1] = excl + a0;
  __syncthreads();
  for (int i = base + t; i < end; i += 256){
    unsigned int p = ebuf[i];
    int dlo = p & (BSZ-1);
    int pos = base + atomicAdd(&c[dlo], 1);
    colb[pos] = (int)(p >> BSH);
  }
}

// ---------------- W pre-split (layer 2 gets k-permuted fragments) ----------------
__global__ __launch_bounds__(256) void wsplit_kernel(const float* __restrict__ W1,
    const float* __restrict__ W2,
    unsigned short* __restrict__ Whf1, unsigned short* __restrict__ Wlf1,
    unsigned short* __restrict__ Whf2, unsigned short* __restrict__ Wlf2){
  int b = blockIdx.x;
  bool layer2 = (b >= 64);
  const float* W = layer2 ? W2 : W1;
  unsigned short* Whf = layer2 ? Whf2 : Whf1;
  unsigned short* Wlf = layer2 ? Wlf2 : Wlf1;
  int t = (b & 63)*256 + threadIdx.x;   // 0..16383
  int k  = t >> 7;
  int nn = t & 127;
  float w = W[t];
  unsigned short h = bf16_rn(w);
  float whf = __uint_as_float(((unsigned int)h) << 16);
  unsigned short l = bf16_rn(w - whf);
  int ks = layer2 ? (((k & 15) << 3) + (k >> 4)) : k;   // col(ks) == k
  int kc = ks >> 5, l4 = (ks >> 3) & 3, e = ks & 7;
  int cf = nn >> 4, l15 = nn & 15;
  int idx = ((kc*8 + cf)*64 + l4*16 + l15)*8 + e;
  Whf[idx] = h; Wlf[idx] = l;
}

// ---------------- Wa dots + logit B-tile + permuted bias + init duties ----------------
__global__ __launch_bounds__(256) void wafrag_kernel(const float* __restrict__ W1,
    const float* __restrict__ W2,
    const float* __restrict__ as1, const float* __restrict__ ad1,
    const float* __restrict__ as2, const float* __restrict__ ad2,
    const float* __restrict__ b1,
    unsigned short* __restrict__ Whfx1, unsigned short* __restrict__ Wlfx1,
    unsigned short* __restrict__ Whfx2, unsigned short* __restrict__ Wlfx2,
    float* __restrict__ bias_perm1,
    unsigned int* __restrict__ mx, int* __restrict__ bcur, int nbuck){
  __shared__ float wa[2][128];
  int layer = blockIdx.x;
  const float* W  = layer ? W2 : W1;
  const float* as = layer ? as2 : as1;
  const float* ad = layer ? ad2 : ad1;
  unsigned short* Whfx = layer ? Whfx2 : Whfx1;
  unsigned short* Wlfx = layer ? Wlfx2 : Wlfx1;
  int t = threadIdx.x;
  if (t < 2) mx[layer*2 + t] = 0u;
  if (layer == 0 && t < nbuck) bcur[t] = t * BCAP;
  if (layer == 0 && t < 128) bias_perm1[t] = b1[colmap(t)];

  int row = t & 127;
  const float* a = (t >> 7) ? ad : as;
  float s = 0.f;
  #pragma unroll 8
  for (int c = 0; c < 128; c += 4){
    float4 wv = *(const float4*)&W[row*128 + c];
    s += wv.x*a[c] + wv.y*a[c+1] + wv.z*a[c+2] + wv.w*a[c+3];
  }
  wa[t >> 7][row] = s;
  __syncthreads();

  int kc = t >> 6, lane = t & 63;
  int l15 = lane & 15, l4 = lane >> 4;
  unsigned short hh[8], ll[8];
  #pragma unroll
  for (int e = 0; e < 8; ++e){
    int ks = (kc*4 + l4)*8 + e;                 // stored slot
    int k  = layer ? colmap(ks) : ks;           // actual k this slot must hold
    float v = (l15 == 0) ? wa[0][k] : ((l15 == 1) ? wa[1][k] : 0.f);
    unsigned short h = bf16_rn(v);
    hh[e] = h;
    ll[e] = bf16_rn(v - __uint_as_float(((unsigned)h) << 16));
  }
  #pragma unroll
  for (int e = 0; e < 8; ++e){ Whfx[t*8 + e] = hh[e]; Wlfx[t*8 + e] = ll[e]; }
}

// ---------------- MFMA bf16 GEMM (2-term) + MFMA logits, 128-row tile ----------------
// Hb stored in PERMUTED row layout: ushort p of row r holds H[r][colmap(p)].
// BF16IN: X is bf16 rows already in permuted order (k-permuted W fragments match).
template<bool BF16IN>
__global__ __launch_bounds__(256) void gemm_al_kernel(const void* __restrict__ Xv,
    const unsigned short* __restrict__ Whf, const unsigned short* __restrict__ Wlf,
    const unsigned short* __restrict__ Whfx, const unsigned short* __restrict__ Wlfx,
    unsigned short* __restrict__ Hb, float* __restrict__ ALs, float* __restrict__ ALd,
    unsigned int* __restrict__ mx, int n)
{
  __shared__ unsigned short Xh[128*128];   // 32 KB
  __shared__ float redS[4], redD[4];
  int tid  = threadIdx.x;
  int lane = tid & 63;
  int wave = tid >> 6;
  int row0 = blockIdx.x * 128;

  if constexpr (BF16IN){
    const uint4* X4 = (const uint4*)Xv;
    #pragma unroll
    for (int it = 0; it < 8; ++it){
      int f  = it*256 + tid;      // 0..2047
      int r  = f >> 4;            // 0..127
      int pg = f & 15;            // 16B group within row
      uint4 v = make_uint4(0u,0u,0u,0u);
      int gr = row0 + r;
      if (gr < n) v = X4[(size_t)gr*16 + pg];
      *(uint4*)&Xh[r*128 + ((pg ^ (r & 7)) << 3)] = v;
    }
  } else {
    const float* X = (const float*)Xv;
    int c4 = tid & 31;
    #pragma unroll 4
    for (int it = 0; it < 16; ++it){
      int f  = it*256 + tid;      // 0..4095
      int r  = f >> 5;            // 0..127
      float4 v = make_float4(0.f,0.f,0.f,0.f);
      int gr = row0 + r;
      if (gr < n) v = ((const float4*)(X + (size_t)gr*D))[c4];
      unsigned short h0 = bf16_rn(v.x);
      unsigned short h1 = bf16_rn(v.y);
      unsigned short h2 = bf16_rn(v.z);
      unsigned short h3 = bf16_rn(v.w);
      int g   = (c4 >> 1) ^ (r & 7);
      int idx = r*128 + (g << 3) + ((c4 & 1) << 2);
      *(uint2*)&Xh[idx] = make_uint2((unsigned)h0 | ((unsigned)h1<<16),
                                     (unsigned)h2 | ((unsigned)h3<<16));
    }
  }
  __syncthreads();

  int l15 = lane & 15;
  int l4  = lane >> 4;

  f32x4 acc[2][8];
  f32x4 acc2[2];
  #pragma unroll
  for (int rf = 0; rf < 2; ++rf){
    #pragma unroll
    for (int cf = 0; cf < 8; ++cf)
      acc[rf][cf] = (f32x4){0.f, 0.f, 0.f, 0.f};
    acc2[rf] = (f32x4){0.f, 0.f, 0.f, 0.f};
  }

  #pragma unroll
  for (int kc = 0; kc < 4; ++kc){
    int g = kc*4 + l4;
    bf16x8 ah[2];
    #pragma unroll
    for (int rf = 0; rf < 2; ++rf){
      int r   = wave*32 + rf*16 + l15;
      int idx = r*128 + ((g ^ (r & 7)) << 3);
      ah[rf] = *(const bf16x8*)&Xh[idx];
    }
    #pragma unroll
    for (int cf = 0; cf < 8; ++cf){
      int foff = ((kc*8 + cf) << 9) + (lane << 3);
      bf16x8 bh = *(const bf16x8*)&Whf[foff];
      bf16x8 bl = *(const bf16x8*)&Wlf[foff];
      #pragma unroll
      for (int rf = 0; rf < 2; ++rf){
        acc[rf][cf] = __builtin_amdgcn_mfma_f32_16x16x32_bf16(ah[rf], bh, acc[rf][cf], 0, 0, 0);
        acc[rf][cf] = __builtin_amdgcn_mfma_f32_16x16x32_bf16(ah[rf], bl, acc[rf][cf], 0, 0, 0);
      }
    }
    {
      int foffx = ((kc << 6) + lane) << 3;
      bf16x8 bhx = *(const bf16x8*)&Whfx[foffx];
      bf16x8 blx = *(const bf16x8*)&Wlfx[foffx];
      #pragma unroll
      for (int rf = 0; rf < 2; ++rf){
        acc2[rf] = __builtin_amdgcn_mfma_f32_16x16x32_bf16(ah[rf], bhx, acc2[rf], 0, 0, 0);
        acc2[rf] = __builtin_amdgcn_mfma_f32_16x16x32_bf16(ah[rf], blx, acc2[rf], 0, 0, 0);
      }
    }
  }

  float ms = -3e38f, md = -3e38f;
  #pragma unroll
  for (int rf = 0; rf < 2; ++rf){
    #pragma unroll
    for (int reg = 0; reg < 4; ++reg){
      int gr = row0 + wave*32 + rf*16 + l4*4 + reg;   // C/D: row=(lane>>4)*4+reg
      if (gr < n){
        unsigned int p0 = (unsigned)bf16_rn(acc[rf][0][reg]) | ((unsigned)bf16_rn(acc[rf][1][reg]) << 16);
        unsigned int p1 = (unsigned)bf16_rn(acc[rf][2][reg]) | ((unsigned)bf16_rn(acc[rf][3][reg]) << 16);
        unsigned int p2 = (unsigned)bf16_rn(acc[rf][4][reg]) | ((unsigned)bf16_rn(acc[rf][5][reg]) << 16);
        unsigned int p3 = (unsigned)bf16_rn(acc[rf][6][reg]) | ((unsigned)bf16_rn(acc[rf][7][reg]) << 16);
        ((uint4*)(Hb + (size_t)gr*D))[l15] = make_uint4(p0, p1, p2, p3);
        if (l15 == 0){      ALs[gr] = acc2[rf][reg]; ms = fmaxf(ms, acc2[rf][reg]); }
        else if (l15 == 1){ ALd[gr] = acc2[rf][reg]; md = fmaxf(md, acc2[rf][reg]); }
      }
    }
  }
  // block-level max reduce -> one atomic pair per block
  #pragma unroll
  for (int off = 32; off >= 1; off >>= 1){
    ms = fmaxf(ms, __shfl_xor(ms, off));
    md = fmaxf(md, __shfl_xor(md, off));
  }
  if (lane == 0){ redS[wave] = ms; redD[wave] = md; }
  __syncthreads();
  if (tid == 0){
    float a = fmaxf(fmaxf(redS[0], redS[1]), fmaxf(redS[2], redS[3]));
    float b = fmaxf(fmaxf(redD[0], redD[1]), fmaxf(redD[2], redD[3]));
    atomicMax(&mx[0], enc_f(a));
    atomicMax(&mx[1], enc_f(b));
  }
}

// ---------------- fused softmax + weighted gather aggregation ----------------
// BF16OUT: write bf16 permuted rows (layer-1 handoff; bias pre-permuted).
// else: un-permute via shuffles and write fp32 (final output).
template<bool BF16OUT>
__global__ __launch_bounds__(256) void agg_kernel(const unsigned short* __restrict__ Hb,
    const float* __restrict__ ALs, const float* __restrict__ ALd,
    const unsigned int* __restrict__ mx,
    const int2* __restrict__ rowrange, const int* __restrict__ colb,
    const float* __restrict__ bias, void* __restrict__ outv, int n)
{
  __shared__ unsigned int sArr[256];
  __shared__ float wArr[256];
  int gtid = blockIdx.x*blockDim.x + threadIdx.x;
  int node = gtid >> 6;
  int lane = threadIdx.x & 63;
  int wbase = threadIdx.x & 192;
  if (node >= n) return;

  float M = lrelu(dec_f(mx[0]) + dec_f(mx[1]));

  int2 rr = rowrange[node];
  int beg = rr.x, end = rr.y;
  float ald = ALd[node];
  float ws = __expf(lrelu(ALs[node] + ald) - M);

  const unsigned int* H2 = (const unsigned int*)Hb;
  unsigned int us = H2[(unsigned)(node*64 + lane)];
  float2 acc; acc.x = ws * bf16_lo_f(us); acc.y = ws * bf16_hi_f(us);
  float zl = 0.f;

  for (int c = beg; c < end; c += 64){
    int j = c + lane;
    bool valid = j < end;
    int s_l = valid ? colb[j] : 0;
    float w_l = valid ? __expf(lrelu(ALs[s_l] + ald) - M) : 0.f;
    zl += w_l;

    sArr[threadIdx.x] = (unsigned)s_l;
    wArr[threadIdx.x] = w_l;

    int cnt = end - c; if (cnt > 64) cnt = 64;
    int q = 0;
    for (; q + 8 <= cnt; q += 8){
      unsigned int ss[8]; float ww[8]; unsigned int u[8];
      #pragma unroll
      for (int p = 0; p < 8; ++p){ ss[p] = sArr[wbase + q + p]; ww[p] = wArr[wbase + q + p]; }
      #pragma unroll
      for (int p = 0; p < 8; ++p) u[p] = H2[(unsigned)(ss[p]*64u + lane)];
      #pragma unroll
      for (int p = 0; p < 8; ++p){
        acc.x += ww[p]*bf16_lo_f(u[p]);
        acc.y += ww[p]*bf16_hi_f(u[p]);
      }
    }
    for (; q < cnt; ++q){
      unsigned int u = H2[(unsigned)(sArr[wbase + q]*64u + lane)];
      float w = wArr[wbase + q];
      acc.x += w*bf16_lo_f(u); acc.y += w*bf16_hi_f(u);
    }
  }

  #pragma unroll
  for (int off = 32; off >= 1; off >>= 1) zl += __shfl_xor(zl, off);
  float zi = 1.f / (zl + ws);
  acc.x *= zi; acc.y *= zi;

  if constexpr (BF16OUT){
    float2 bp = ((const float2*)bias)[lane];
    unsigned int w = (unsigned)bf16_rn(acc.x + bp.x) | ((unsigned)bf16_rn(acc.y + bp.y) << 16);
    ((unsigned int*)outv)[(unsigned)(node*64 + lane)] = w;
  } else {
    int q0 = (lane >> 4) + ((lane & 7) << 3);
    int q1 = q0 + 4;
    int hsel = (lane >> 3) & 1;
    float x0 = __shfl(acc.x, q0), y0 = __shfl(acc.y, q0);
    float x1 = __shfl(acc.x, q1), y1 = __shfl(acc.y, q1);
    float v0 = hsel ? y0 : x0;
    float v1 = hsel ? y1 : x1;
    float2 b2 = ((const float2*)bias)[lane];
    ((float2*)outv)[(size_t)node*64 + lane] = make_float2(v0 + b2.x, v1 + b2.y);
  }
}

// ---------------- launch ----------------
extern "C" void kernel_launch(void* const* d_in, const int* in_sizes, int n_in,
                              void* d_out, int out_size, void* d_ws, size_t ws_size,
                              hipStream_t stream)
{
  const float* x   = (const float*)d_in[0];
  const int*   ei  = (const int*)  d_in[1];
  const float* W1  = (const float*)d_in[2];
  const float* as1 = (const float*)d_in[3];
  const float* ad1 = (const float*)d_in[4];
  const float* b1  = (const float*)d_in[5];
  const float* W2  = (const float*)d_in[6];
  const float* as2 = (const float*)d_in[7];
  const float* ad2 = (const float*)d_in[8];
  const float* b2  = (const float*)d_in[9];

  int n = in_sizes[0] / D;
  int E = in_sizes[1] / 2;
  const int* src = ei;
  const int* dst = ei + E;
  int nbuck = (n + BSZ - 1) >> BSH;

  char* base = (char*)d_ws;
  size_t off = 0;
  auto alloc = [&](size_t bytes) -> char* {
    char* p = base + off;
    off = (off + bytes + 255) & ~(size_t)255;
    return p;
  };
  unsigned short* hb  = (unsigned short*)alloc((size_t)n*D*2);
  unsigned short* hb2 = (unsigned short*)alloc((size_t)n*D*2);
  float* als    = (float*)alloc((size_t)n*4);
  float* ald    = (float*)alloc((size_t)n*4);
  int2* rowrange = (int2*)alloc((size_t)n*8);
  int* bcur     = (int*)alloc(256*4);
  unsigned int* mx = (unsigned int*)alloc(4*4);
  float* bias_perm1 = (float*)alloc(128*4);
  unsigned short* whf1 = (unsigned short*)alloc(16384*2);
  unsigned short* wlf1 = (unsigned short*)alloc(16384*2);
  unsigned short* whf2 = (unsigned short*)alloc(16384*2);
  unsigned short* wlf2 = (unsigned short*)alloc(16384*2);
  unsigned short* whfx1 = (unsigned short*)alloc(2048*2);
  unsigned short* wlfx1 = (unsigned short*)alloc(2048*2);
  unsigned short* whfx2 = (unsigned short*)alloc(2048*2);
  unsigned short* wlfx2 = (unsigned short*)alloc(2048*2);
  unsigned int* ebuf = (unsigned int*)alloc((size_t)nbuck*BCAP*4);
  int* colb = (int*)alloc((size_t)nbuck*BCAP*4);

  float* out = (float*)d_out;

  // prep: 2 dispatches
  wsplit_kernel<<<128, 256, 0, stream>>>(W1, W2, whf1, wlf1, whf2, wlf2);
  wafrag_kernel<<<2, 256, 0, stream>>>(W1, W2, as1, ad1, as2, ad2, b1,
                                       whfx1, wlfx1, whfx2, wlfx2,
                                       bias_perm1, mx, bcur, nbuck);

  // CSR build: 2 dispatches
  int sc_blocks = (E + SC_CHUNK - 1) / SC_CHUNK;
  bucket_scatter_kernel<<<sc_blocks, 1024, 0, stream>>>(src, dst, E, bcur, ebuf, nbuck);
  bucket_csr_kernel    <<<nbuck, 256, 0, stream>>>(ebuf, bcur, rowrange, colb, n, nbuck);

  int ntiles = (n + 127)/128;
  int aggblocks = (int)(((size_t)n*64 + 255)/256);

  gemm_al_kernel<false><<<ntiles, 256, 0, stream>>>(x,   whf1, wlf1, whfx1, wlfx1, hb, als, ald, mx,   n);
  agg_kernel<true>     <<<aggblocks, 256, 0, stream>>>(hb, als, ald, mx,   rowrange, colb, bias_perm1, hb2, n);
  gemm_al_kernel<true> <<<ntiles, 256, 0, stream>>>(hb2, whf2, wlf2, whfx2, wlfx2, hb, als, ald, mx+2, n);
  agg_kernel<false>    <<<aggblocks, 256, 0, stream>>>(hb, als, ald, mx+2, rowrange, colb, b2, out, n);
}

// Round 15
// 272.849 us; speedup vs baseline: 1.1387x; 1.0232x over previous
//
#include <hip/hip_runtime.h>
#include <hip/hip_bf16.h>
#include <math.h>

#define D 128
#define LRELU_SLOPE 0.2f
#define BSH 9
#define BSZ 512
#define BCAP 10240
#define SC_CHUNK 16384

typedef __attribute__((ext_vector_type(8))) short bf16x8;
typedef __attribute__((ext_vector_type(4))) float f32x4;

__device__ __forceinline__ float lrelu(float x){ return x > 0.f ? x : LRELU_SLOPE * x; }

__device__ __forceinline__ unsigned short bf16_rn(float x){
  unsigned int u = __float_as_uint(x);
  return (unsigned short)((u + 0x7FFFu + ((u >> 16) & 1u)) >> 16);
}
__device__ __forceinline__ float bf16_lo_f(unsigned int u){ return __uint_as_float(u << 16); }
__device__ __forceinline__ float bf16_hi_f(unsigned int u){ return __uint_as_float(u & 0xFFFF0000u); }

__device__ __forceinline__ unsigned int enc_f(float f){
  unsigned int u = __float_as_uint(f);
  return (u & 0x80000000u) ? ~u : (u | 0x80000000u);
}
__device__ __forceinline__ float dec_f(unsigned int e){
  return __uint_as_float((e & 0x80000000u) ? (e & 0x7FFFFFFFu) : ~e);
}

// permuted position p -> actual column
__device__ __forceinline__ int colmap(int p){ return ((p & 7) << 4) + (p >> 3); }

// ---------------- merged prep: W pre-split (blocks 0..127) + wafrag (blocks 128..129) ----------------
__global__ __launch_bounds__(256) void prep_kernel(const float* __restrict__ W1,
    const float* __restrict__ W2,
    const float* __restrict__ as1, const float* __restrict__ ad1,
    const float* __restrict__ as2, const float* __restrict__ ad2,
    const float* __restrict__ b1,
    unsigned short* __restrict__ Whf1, unsigned short* __restrict__ Wlf1,
    unsigned short* __restrict__ Whf2, unsigned short* __restrict__ Wlf2,
    unsigned short* __restrict__ Whfx1, unsigned short* __restrict__ Wlfx1,
    unsigned short* __restrict__ Whfx2, unsigned short* __restrict__ Wlfx2,
    float* __restrict__ bias_perm1,
    unsigned int* __restrict__ mx, int* __restrict__ bcur, int nbuck)
{
  __shared__ float wa[2][128];
  int blk = blockIdx.x;
  if (blk < 128){
    // wsplit: layer 2 gets k-permuted fragments
    bool layer2 = (blk >= 64);
    const float* W = layer2 ? W2 : W1;
    unsigned short* Whf = layer2 ? Whf2 : Whf1;
    unsigned short* Wlf = layer2 ? Wlf2 : Wlf1;
    int t = (blk & 63)*256 + threadIdx.x;   // 0..16383
    int k  = t >> 7;
    int nn = t & 127;
    float w = W[t];
    unsigned short h = bf16_rn(w);
    float whf = __uint_as_float(((unsigned int)h) << 16);
    unsigned short l = bf16_rn(w - whf);
    int ks = layer2 ? (((k & 15) << 3) + (k >> 4)) : k;   // col(ks) == k
    int kc = ks >> 5, l4 = (ks >> 3) & 3, e = ks & 7;
    int cf = nn >> 4, l15 = nn & 15;
    int idx = ((kc*8 + cf)*64 + l4*16 + l15)*8 + e;
    Whf[idx] = h; Wlf[idx] = l;
    return;
  }
  // wafrag: logit B-tile + permuted bias + init duties
  int layer = blk - 128;
  const float* W  = layer ? W2 : W1;
  const float* as = layer ? as2 : as1;
  const float* ad = layer ? ad2 : ad1;
  unsigned short* Whfx = layer ? Whfx2 : Whfx1;
  unsigned short* Wlfx = layer ? Wlfx2 : Wlfx1;
  int t = threadIdx.x;
  if (t < 2) mx[layer*2 + t] = 0u;
  if (layer == 0 && t < nbuck) bcur[t] = t * BCAP;
  if (layer == 0 && t < 128) bias_perm1[t] = b1[colmap(t)];

  int row = t & 127;
  const float* a = (t >> 7) ? ad : as;
  float s = 0.f;
  #pragma unroll 8
  for (int c = 0; c < 128; c += 4){
    float4 wv = *(const float4*)&W[row*128 + c];
    s += wv.x*a[c] + wv.y*a[c+1] + wv.z*a[c+2] + wv.w*a[c+3];
  }
  wa[t >> 7][row] = s;
  __syncthreads();

  int kc = t >> 6, lane = t & 63;
  int l15 = lane & 15, l4 = lane >> 4;
  unsigned short hh[8], ll[8];
  #pragma unroll
  for (int e = 0; e < 8; ++e){
    int ks = (kc*4 + l4)*8 + e;                 // stored slot
    int k  = layer ? colmap(ks) : ks;           // actual k this slot must hold
    float v = (l15 == 0) ? wa[0][k] : ((l15 == 1) ? wa[1][k] : 0.f);
    unsigned short h = bf16_rn(v);
    hh[e] = h;
    ll[e] = bf16_rn(v - __uint_as_float(((unsigned)h) << 16));
  }
  #pragma unroll
  for (int e = 0; e < 8; ++e){ Whfx[t*8 + e] = hh[e]; Wlfx[t*8 + e] = ll[e]; }
}

__global__ __launch_bounds__(256) void bucket_csr_kernel(const unsigned int* __restrict__ ebuf,
    const int* __restrict__ bcur, int2* __restrict__ rowrange, int* __restrict__ colb,
    int n, int nbuck){
  __shared__ int c[512];
  __shared__ int ps[256];
  int b = blockIdx.x;
  int t = threadIdx.x;
  int base = b * BCAP;
  int end  = bcur[b];
  c[t] = 0; c[t+256] = 0;
  __syncthreads();
  for (int i = base + t; i < end; i += 256)
    atomicAdd(&c[ebuf[i] & (BSZ-1)], 1);
  __syncthreads();
  int a0 = c[2*t], a1 = c[2*t+1];
  int pair = a0 + a1;
  ps[t] = pair;
  __syncthreads();
  #pragma unroll
  for (int d = 1; d < 256; d <<= 1){
    int add = (t >= d) ? ps[t-d] : 0;
    __syncthreads();
    ps[t] += add;
    __syncthreads();
  }
  int excl = ps[t] - pair;
  __syncthreads();
  int lo = b << BSH;
  int g0 = lo + 2*t, g1 = g0 + 1;
  if (g0 < n) rowrange[g0] = make_int2(base + excl,      base + excl + a0);
  if (g1 < n) rowrange[g1] = make_int2(base + excl + a0, base + excl + a0 + a1);
  c[2*t]   = excl;
  c[2*t+1] = excl + a0;
  __syncthreads();
  for (int i = base + t; i < end; i += 256){
    unsigned int p = ebuf[i];
    int dlo = p & (BSZ-1);
    int pos = base + atomicAdd(&c[dlo], 1);
    colb[pos] = (int)(p >> BSH);
  }
}

// ---------------- FAT kernel: bucket_scatter (blocks 0..sc_blocks-1) + gemm1 fp32 ----------------
// Scatter blocks first so they retire early and their CU slots refill with gemm blocks.
__global__ __launch_bounds__(256) void gemm1_scatter_kernel(const float* __restrict__ X,
    const unsigned short* __restrict__ Whf, const unsigned short* __restrict__ Wlf,
    const unsigned short* __restrict__ Whfx, const unsigned short* __restrict__ Wlfx,
    unsigned short* __restrict__ Hb, float* __restrict__ ALs, float* __restrict__ ALd,
    unsigned int* __restrict__ mx, int n, int sc_blocks,
    const int* __restrict__ src, const int* __restrict__ dst, int E,
    int* __restrict__ bcur, unsigned int* __restrict__ ebuf, int nbuck)
{
  __shared__ unsigned short Xh[128*128];   // 32 KB (scatter overlays h/cb on it)
  __shared__ float redS[4], redD[4];
  int tid  = threadIdx.x;

  if (blockIdx.x < sc_blocks){
    int* h  = (int*)Xh;
    int* cb = h + 256;
    int base = blockIdx.x * SC_CHUNK;
    int end = base + SC_CHUNK; if (end > E) end = E;
    h[tid] = 0;
    __syncthreads();
    for (int e = base + tid; e < end; e += 256)
      atomicAdd(&h[dst[e] >> BSH], 1);
    __syncthreads();
    if (tid < nbuck){
      cb[tid] = h[tid] ? atomicAdd(&bcur[tid], h[tid]) : 0;
      h[tid] = 0;
    }
    __syncthreads();
    for (int e = base + tid; e < end; e += 256){
      int d = dst[e];
      int b = d >> BSH;
      int lpos = atomicAdd(&h[b], 1);
      ebuf[cb[b] + lpos] = ((unsigned int)src[e] << BSH) | (unsigned int)(d & (BSZ-1));
    }
    return;
  }

  int lane = tid & 63;
  int wave = tid >> 6;
  int row0 = (blockIdx.x - sc_blocks) * 128;
  int c4   = tid & 31;

  #pragma unroll 4
  for (int it = 0; it < 16; ++it){
    int f  = it*256 + tid;      // 0..4095
    int r  = f >> 5;            // 0..127
    float4 v = make_float4(0.f,0.f,0.f,0.f);
    int gr = row0 + r;
    if (gr < n) v = ((const float4*)(X + (size_t)gr*D))[c4];
    unsigned short h0 = bf16_rn(v.x);
    unsigned short h1 = bf16_rn(v.y);
    unsigned short h2 = bf16_rn(v.z);
    unsigned short h3 = bf16_rn(v.w);
    int g   = (c4 >> 1) ^ (r & 7);
    int idx = r*128 + (g << 3) + ((c4 & 1) << 2);
    *(uint2*)&Xh[idx] = make_uint2((unsigned)h0 | ((unsigned)h1<<16),
                                   (unsigned)h2 | ((unsigned)h3<<16));
  }
  __syncthreads();

  int l15 = lane & 15;
  int l4  = lane >> 4;

  f32x4 acc[2][8];
  f32x4 acc2[2];
  #pragma unroll
  for (int rf = 0; rf < 2; ++rf){
    #pragma unroll
    for (int cf = 0; cf < 8; ++cf)
      acc[rf][cf] = (f32x4){0.f, 0.f, 0.f, 0.f};
    acc2[rf] = (f32x4){0.f, 0.f, 0.f, 0.f};
  }

  #pragma unroll
  for (int kc = 0; kc < 4; ++kc){
    int g = kc*4 + l4;
    bf16x8 ah[2];
    #pragma unroll
    for (int rf = 0; rf < 2; ++rf){
      int r   = wave*32 + rf*16 + l15;
      int idx = r*128 + ((g ^ (r & 7)) << 3);
      ah[rf] = *(const bf16x8*)&Xh[idx];
    }
    #pragma unroll
    for (int cf = 0; cf < 8; ++cf){
      int foff = ((kc*8 + cf) << 9) + (lane << 3);
      bf16x8 bh = *(const bf16x8*)&Whf[foff];
      bf16x8 bl = *(const bf16x8*)&Wlf[foff];
      #pragma unroll
      for (int rf = 0; rf < 2; ++rf){
        acc[rf][cf] = __builtin_amdgcn_mfma_f32_16x16x32_bf16(ah[rf], bh, acc[rf][cf], 0, 0, 0);
        acc[rf][cf] = __builtin_amdgcn_mfma_f32_16x16x32_bf16(ah[rf], bl, acc[rf][cf], 0, 0, 0);
      }
    }
    {
      int foffx = ((kc << 6) + lane) << 3;
      bf16x8 bhx = *(const bf16x8*)&Whfx[foffx];
      bf16x8 blx = *(const bf16x8*)&Wlfx[foffx];
      #pragma unroll
      for (int rf = 0; rf < 2; ++rf){
        acc2[rf] = __builtin_amdgcn_mfma_f32_16x16x32_bf16(ah[rf], bhx, acc2[rf], 0, 0, 0);
        acc2[rf] = __builtin_amdgcn_mfma_f32_16x16x32_bf16(ah[rf], blx, acc2[rf], 0, 0, 0);
      }
    }
  }

  float ms = -3e38f, md = -3e38f;
  #pragma unroll
  for (int rf = 0; rf < 2; ++rf){
    #pragma unroll
    for (int reg = 0; reg < 4; ++reg){
      int gr = row0 + wave*32 + rf*16 + l4*4 + reg;   // C/D: row=(lane>>4)*4+reg
      if (gr < n){
        unsigned int p0 = (unsigned)bf16_rn(acc[rf][0][reg]) | ((unsigned)bf16_rn(acc[rf][1][reg]) << 16);
        unsigned int p1 = (unsigned)bf16_rn(acc[rf][2][reg]) | ((unsigned)bf16_rn(acc[rf][3][reg]) << 16);
        unsigned int p2 = (unsigned)bf16_rn(acc[rf][4][reg]) | ((unsigned)bf16_rn(acc[rf][5][reg]) << 16);
        unsigned int p3 = (unsigned)bf16_rn(acc[rf][6][reg]) | ((unsigned)bf16_rn(acc[rf][7][reg]) << 16);
        ((uint4*)(Hb + (size_t)gr*D))[l15] = make_uint4(p0, p1, p2, p3);
        if (l15 == 0){      ALs[gr] = acc2[rf][reg]; ms = fmaxf(ms, acc2[rf][reg]); }
        else if (l15 == 1){ ALd[gr] = acc2[rf][reg]; md = fmaxf(md, acc2[rf][reg]); }
      }
    }
  }
  #pragma unroll
  for (int off = 32; off >= 1; off >>= 1){
    ms = fmaxf(ms, __shfl_xor(ms, off));
    md = fmaxf(md, __shfl_xor(md, off));
  }
  if (lane == 0){ redS[wave] = ms; redD[wave] = md; }
  __syncthreads();
  if (tid == 0){
    float a = fmaxf(fmaxf(redS[0], redS[1]), fmaxf(redS[2], redS[3]));
    float b = fmaxf(fmaxf(redD[0], redD[1]), fmaxf(redD[2], redD[3]));
    atomicMax(&mx[0], enc_f(a));
    atomicMax(&mx[1], enc_f(b));
  }
}

// ---------------- MFMA bf16 GEMM layer 2 (bf16 permuted input), 128-row tile ----------------
__global__ __launch_bounds__(256) void gemm2_kernel(const unsigned short* __restrict__ Xb,
    const unsigned short* __restrict__ Whf, const unsigned short* __restrict__ Wlf,
    const unsigned short* __restrict__ Whfx, const unsigned short* __restrict__ Wlfx,
    unsigned short* __restrict__ Hb, float* __restrict__ ALs, float* __restrict__ ALd,
    unsigned int* __restrict__ mx, int n)
{
  __shared__ unsigned short Xh[128*128];
  __shared__ float redS[4], redD[4];
  int tid  = threadIdx.x;
  int lane = tid & 63;
  int wave = tid >> 6;
  int row0 = blockIdx.x * 128;

  const uint4* X4 = (const uint4*)Xb;
  #pragma unroll
  for (int it = 0; it < 8; ++it){
    int f  = it*256 + tid;      // 0..2047
    int r  = f >> 4;            // 0..127
    int pg = f & 15;            // 16B group within row
    uint4 v = make_uint4(0u,0u,0u,0u);
    int gr = row0 + r;
    if (gr < n) v = X4[(size_t)gr*16 + pg];
    *(uint4*)&Xh[r*128 + ((pg ^ (r & 7)) << 3)] = v;
  }
  __syncthreads();

  int l15 = lane & 15;
  int l4  = lane >> 4;

  f32x4 acc[2][8];
  f32x4 acc2[2];
  #pragma unroll
  for (int rf = 0; rf < 2; ++rf){
    #pragma unroll
    for (int cf = 0; cf < 8; ++cf)
      acc[rf][cf] = (f32x4){0.f, 0.f, 0.f, 0.f};
    acc2[rf] = (f32x4){0.f, 0.f, 0.f, 0.f};
  }

  #pragma unroll
  for (int kc = 0; kc < 4; ++kc){
    int g = kc*4 + l4;
    bf16x8 ah[2];
    #pragma unroll
    for (int rf = 0; rf < 2; ++rf){
      int r   = wave*32 + rf*16 + l15;
      int idx = r*128 + ((g ^ (r & 7)) << 3);
      ah[rf] = *(const bf16x8*)&Xh[idx];
    }
    #pragma unroll
    for (int cf = 0; cf < 8; ++cf){
      int foff = ((kc*8 + cf) << 9) + (lane << 3);
      bf16x8 bh = *(const bf16x8*)&Whf[foff];
      bf16x8 bl = *(const bf16x8*)&Wlf[foff];
      #pragma unroll
      for (int rf = 0; rf < 2; ++rf){
        acc[rf][cf] = __builtin_amdgcn_mfma_f32_16x16x32_bf16(ah[rf], bh, acc[rf][cf], 0, 0, 0);
        acc[rf][cf] = __builtin_amdgcn_mfma_f32_16x16x32_bf16(ah[rf], bl, acc[rf][cf], 0, 0, 0);
      }
    }
    {
      int foffx = ((kc << 6) + lane) << 3;
      bf16x8 bhx = *(const bf16x8*)&Whfx[foffx];
      bf16x8 blx = *(const bf16x8*)&Wlfx[foffx];
      #pragma unroll
      for (int rf = 0; rf < 2; ++rf){
        acc2[rf] = __builtin_amdgcn_mfma_f32_16x16x32_bf16(ah[rf], bhx, acc2[rf], 0, 0, 0);
        acc2[rf] = __builtin_amdgcn_mfma_f32_16x16x32_bf16(ah[rf], blx, acc2[rf], 0, 0, 0);
      }
    }
  }

  float ms = -3e38f, md = -3e38f;
  #pragma unroll
  for (int rf = 0; rf < 2; ++rf){
    #pragma unroll
    for (int reg = 0; reg < 4; ++reg){
      int gr = row0 + wave*32 + rf*16 + l4*4 + reg;
      if (gr < n){
        unsigned int p0 = (unsigned)bf16_rn(acc[rf][0][reg]) | ((unsigned)bf16_rn(acc[rf][1][reg]) << 16);
        unsigned int p1 = (unsigned)bf16_rn(acc[rf][2][reg]) | ((unsigned)bf16_rn(acc[rf][3][reg]) << 16);
        unsigned int p2 = (unsigned)bf16_rn(acc[rf][4][reg]) | ((unsigned)bf16_rn(acc[rf][5][reg]) << 16);
        unsigned int p3 = (unsigned)bf16_rn(acc[rf][6][reg]) | ((unsigned)bf16_rn(acc[rf][7][reg]) << 16);
        ((uint4*)(Hb + (size_t)gr*D))[l15] = make_uint4(p0, p1, p2, p3);
        if (l15 == 0){      ALs[gr] = acc2[rf][reg]; ms = fmaxf(ms, acc2[rf][reg]); }
        else if (l15 == 1){ ALd[gr] = acc2[rf][reg]; md = fmaxf(md, acc2[rf][reg]); }
      }
    }
  }
  #pragma unroll
  for (int off = 32; off >= 1; off >>= 1){
    ms = fmaxf(ms, __shfl_xor(ms, off));
    md = fmaxf(md, __shfl_xor(md, off));
  }
  if (lane == 0){ redS[wave] = ms; redD[wave] = md; }
  __syncthreads();
  if (tid == 0){
    float a = fmaxf(fmaxf(redS[0], redS[1]), fmaxf(redS[2], redS[3]));
    float b = fmaxf(fmaxf(redD[0], redD[1]), fmaxf(redD[2], redD[3]));
    atomicMax(&mx[0], enc_f(a));
    atomicMax(&mx[1], enc_f(b));
  }
}

// ---------------- fused softmax + weighted gather aggregation ----------------
template<bool BF16OUT>
__global__ __launch_bounds__(256) void agg_kernel(const unsigned short* __restrict__ Hb,
    const float* __restrict__ ALs, const float* __restrict__ ALd,
    const unsigned int* __restrict__ mx,
    const int2* __restrict__ rowrange, const int* __restrict__ colb,
    const float* __restrict__ bias, void* __restrict__ outv, int n)
{
  __shared__ unsigned int sArr[256];
  __shared__ float wArr[256];
  int gtid = blockIdx.x*blockDim.x + threadIdx.x;
  int node = gtid >> 6;
  int lane = threadIdx.x & 63;
  int wbase = threadIdx.x & 192;
  if (node >= n) return;

  float M = lrelu(dec_f(mx[0]) + dec_f(mx[1]));

  int2 rr = rowrange[node];
  int beg = rr.x, end = rr.y;
  float ald = ALd[node];
  float ws = __expf(lrelu(ALs[node] + ald) - M);

  const unsigned int* H2 = (const unsigned int*)Hb;
  unsigned int us = H2[(unsigned)(node*64 + lane)];
  float2 acc; acc.x = ws * bf16_lo_f(us); acc.y = ws * bf16_hi_f(us);
  float zl = 0.f;

  for (int c = beg; c < end; c += 64){
    int j = c + lane;
    bool valid = j < end;
    int s_l = valid ? colb[j] : 0;
    float w_l = valid ? __expf(lrelu(ALs[s_l] + ald) - M) : 0.f;
    zl += w_l;

    sArr[threadIdx.x] = (unsigned)s_l;
    wArr[threadIdx.x] = w_l;

    int cnt = end - c; if (cnt > 64) cnt = 64;
    int q = 0;
    for (; q + 8 <= cnt; q += 8){
      unsigned int ss[8]; float ww[8]; unsigned int u[8];
      #pragma unroll
      for (int p = 0; p < 8; ++p){ ss[p] = sArr[wbase + q + p]; ww[p] = wArr[wbase + q + p]; }
      #pragma unroll
      for (int p = 0; p < 8; ++p) u[p] = H2[(unsigned)(ss[p]*64u + lane)];
      #pragma unroll
      for (int p = 0; p < 8; ++p){
        acc.x += ww[p]*bf16_lo_f(u[p]);
        acc.y += ww[p]*bf16_hi_f(u[p]);
      }
    }
    for (; q < cnt; ++q){
      unsigned int u = H2[(unsigned)(sArr[wbase + q]*64u + lane)];
      float w = wArr[wbase + q];
      acc.x += w*bf16_lo_f(u); acc.y += w*bf16_hi_f(u);
    }
  }

  #pragma unroll
  for (int off = 32; off >= 1; off >>= 1) zl += __shfl_xor(zl, off);
  float zi = 1.f / (zl + ws);
  acc.x *= zi; acc.y *= zi;

  if constexpr (BF16OUT){
    float2 bp = ((const float2*)bias)[lane];
    unsigned int w = (unsigned)bf16_rn(acc.x + bp.x) | ((unsigned)bf16_rn(acc.y + bp.y) << 16);
    ((unsigned int*)outv)[(unsigned)(node*64 + lane)] = w;
  } else {
    int q0 = (lane >> 4) + ((lane & 7) << 3);
    int q1 = q0 + 4;
    int hsel = (lane >> 3) & 1;
    float x0 = __shfl(acc.x, q0), y0 = __shfl(acc.y, q0);
    float x1 = __shfl(acc.x, q1), y1 = __shfl(acc.y, q1);
    float v0 = hsel ? y0 : x0;
    float v1 = hsel ? y1 : x1;
    float2 b2 = ((const float2*)bias)[lane];
    ((float2*)outv)[(size_t)node*64 + lane] = make_float2(v0 + b2.x, v1 + b2.y);
  }
}

// ---------------- launch ----------------
extern "C" void kernel_launch(void* const* d_in, const int* in_sizes, int n_in,
                              void* d_out, int out_size, void* d_ws, size_t ws_size,
                              hipStream_t stream)
{
  const float* x   = (const float*)d_in[0];
  const int*   ei  = (const int*)  d_in[1];
  const float* W1  = (const float*)d_in[2];
  const float* as1 = (const float*)d_in[3];
  const float* ad1 = (const float*)d_in[4];
  const float* b1  = (const float*)d_in[5];
  const float* W2  = (const float*)d_in[6];
  const float* as2 = (const float*)d_in[7];
  const float* ad2 = (const float*)d_in[8];
  const float* b2  = (const float*)d_in[9];

  int n = in_sizes[0] / D;
  int E = in_sizes[1] / 2;
  const int* src = ei;
  const int* dst = ei + E;
  int nbuck = (n + BSZ - 1) >> BSH;

  char* base = (char*)d_ws;
  size_t off = 0;
  auto alloc = [&](size_t bytes) -> char* {
    char* p = base + off;
    off = (off + bytes + 255) & ~(size_t)255;
    return p;
  };
  unsigned short* hb  = (unsigned short*)alloc((size_t)n*D*2);
  unsigned short* hb2 = (unsigned short*)alloc((size_t)n*D*2);
  float* als    = (float*)alloc((size_t)n*4);
  float* ald    = (float*)alloc((size_t)n*4);
  int2* rowrange = (int2*)alloc((size_t)n*8);
  int* bcur     = (int*)alloc(256*4);
  unsigned int* mx = (unsigned int*)alloc(4*4);
  float* bias_perm1 = (float*)alloc(128*4);
  unsigned short* whf1 = (unsigned short*)alloc(16384*2);
  unsigned short* wlf1 = (unsigned short*)alloc(16384*2);
  unsigned short* whf2 = (unsigned short*)alloc(16384*2);
  unsigned short* wlf2 = (unsigned short*)alloc(16384*2);
  unsigned short* whfx1 = (unsigned short*)alloc(2048*2);
  unsigned short* wlfx1 = (unsigned short*)alloc(2048*2);
  unsigned short* whfx2 = (unsigned short*)alloc(2048*2);
  unsigned short* wlfx2 = (unsigned short*)alloc(2048*2);
  unsigned int* ebuf = (unsigned int*)alloc((size_t)nbuck*BCAP*4);
  int* colb = (int*)alloc((size_t)nbuck*BCAP*4);

  float* out = (float*)d_out;

  int sc_blocks = (E + SC_CHUNK - 1) / SC_CHUNK;
  int ntiles = (n + 127)/128;
  int aggblocks = (int)(((size_t)n*64 + 255)/256);

  // 1: prep (wsplit + wafrag + inits)
  prep_kernel<<<130, 256, 0, stream>>>(W1, W2, as1, ad1, as2, ad2, b1,
                                       whf1, wlf1, whf2, wlf2,
                                       whfx1, wlfx1, whfx2, wlfx2,
                                       bias_perm1, mx, bcur, nbuck);
  // 2: fat — scatter (first sc_blocks) + gemm1
  gemm1_scatter_kernel<<<sc_blocks + ntiles, 256, 0, stream>>>(
      x, whf1, wlf1, whfx1, wlfx1, hb, als, ald, mx, n, sc_blocks,
      src, dst, E, bcur, ebuf, nbuck);
  // 3: csr finish
  bucket_csr_kernel<<<nbuck, 256, 0, stream>>>(ebuf, bcur, rowrange, colb, n, nbuck);
  // 4-6: agg1 -> gemm2 -> agg2
  agg_kernel<true>  <<<aggblocks, 256, 0, stream>>>(hb, als, ald, mx,   rowrange, colb, bias_perm1, hb2, n);
  gemm2_kernel      <<<ntiles, 256, 0, stream>>>(hb2, whf2, wlf2, whfx2, wlfx2, hb, als, ald, mx+2, n);
  agg_kernel<false> <<<aggblocks, 256, 0, stream>>>(hb, als, ald, mx+2, rowrange, colb, b2, out, n);
}

// Round 16
// 264.658 us; speedup vs baseline: 1.1739x; 1.0309x over previous
//
#include <hip/hip_runtime.h>
#include <hip/hip_bf16.h>
#include <math.h>

#define D 128
#define LRELU_SLOPE 0.2f
#define BSH 9
#define BSZ 512
#define BCAP 10240
#define SC_CHUNK 4096   // sized for 256-thread scatter blocks: 392 blocks -> 100K threads

typedef __attribute__((ext_vector_type(8))) short bf16x8;
typedef __attribute__((ext_vector_type(4))) float f32x4;

__device__ __forceinline__ float lrelu(float x){ return x > 0.f ? x : LRELU_SLOPE * x; }

__device__ __forceinline__ unsigned short bf16_rn(float x){
  unsigned int u = __float_as_uint(x);
  return (unsigned short)((u + 0x7FFFu + ((u >> 16) & 1u)) >> 16);
}
__device__ __forceinline__ float bf16_lo_f(unsigned int u){ return __uint_as_float(u << 16); }
__device__ __forceinline__ float bf16_hi_f(unsigned int u){ return __uint_as_float(u & 0xFFFF0000u); }

__device__ __forceinline__ unsigned int enc_f(float f){
  unsigned int u = __float_as_uint(f);
  return (u & 0x80000000u) ? ~u : (u | 0x80000000u);
}
__device__ __forceinline__ float dec_f(unsigned int e){
  return __uint_as_float((e & 0x80000000u) ? (e & 0x7FFFFFFFu) : ~e);
}

// permuted position p -> actual column
__device__ __forceinline__ int colmap(int p){ return ((p & 7) << 4) + (p >> 3); }

// ---------------- merged prep: W pre-split (blocks 0..127) + wafrag (blocks 128..129) ----------------
__global__ __launch_bounds__(256) void prep_kernel(const float* __restrict__ W1,
    const float* __restrict__ W2,
    const float* __restrict__ as1, const float* __restrict__ ad1,
    const float* __restrict__ as2, const float* __restrict__ ad2,
    const float* __restrict__ b1,
    unsigned short* __restrict__ Whf1, unsigned short* __restrict__ Wlf1,
    unsigned short* __restrict__ Whf2, unsigned short* __restrict__ Wlf2,
    unsigned short* __restrict__ Whfx1, unsigned short* __restrict__ Wlfx1,
    unsigned short* __restrict__ Whfx2, unsigned short* __restrict__ Wlfx2,
    float* __restrict__ bias_perm1,
    unsigned int* __restrict__ mx, int* __restrict__ bcur, int nbuck)
{
  __shared__ float wa[2][128];
  int blk = blockIdx.x;
  if (blk < 128){
    bool layer2 = (blk >= 64);
    const float* W = layer2 ? W2 : W1;
    unsigned short* Whf = layer2 ? Whf2 : Whf1;
    unsigned short* Wlf = layer2 ? Wlf2 : Wlf1;
    int t = (blk & 63)*256 + threadIdx.x;   // 0..16383
    int k  = t >> 7;
    int nn = t & 127;
    float w = W[t];
    unsigned short h = bf16_rn(w);
    float whf = __uint_as_float(((unsigned int)h) << 16);
    unsigned short l = bf16_rn(w - whf);
    int ks = layer2 ? (((k & 15) << 3) + (k >> 4)) : k;   // col(ks) == k
    int kc = ks >> 5, l4 = (ks >> 3) & 3, e = ks & 7;
    int cf = nn >> 4, l15 = nn & 15;
    int idx = ((kc*8 + cf)*64 + l4*16 + l15)*8 + e;
    Whf[idx] = h; Wlf[idx] = l;
    return;
  }
  int layer = blk - 128;
  const float* W  = layer ? W2 : W1;
  const float* as = layer ? as2 : as1;
  const float* ad = layer ? ad2 : ad1;
  unsigned short* Whfx = layer ? Whfx2 : Whfx1;
  unsigned short* Wlfx = layer ? Wlfx2 : Wlfx1;
  int t = threadIdx.x;
  if (t < 2) mx[layer*2 + t] = 0u;
  if (layer == 0 && t < nbuck) bcur[t] = t * BCAP;
  if (layer == 0 && t < 128) bias_perm1[t] = b1[colmap(t)];

  int row = t & 127;
  const float* a = (t >> 7) ? ad : as;
  float s = 0.f;
  #pragma unroll 8
  for (int c = 0; c < 128; c += 4){
    float4 wv = *(const float4*)&W[row*128 + c];
    s += wv.x*a[c] + wv.y*a[c+1] + wv.z*a[c+2] + wv.w*a[c+3];
  }
  wa[t >> 7][row] = s;
  __syncthreads();

  int kc = t >> 6, lane = t & 63;
  int l15 = lane & 15, l4 = lane >> 4;
  unsigned short hh[8], ll[8];
  #pragma unroll
  for (int e = 0; e < 8; ++e){
    int ks = (kc*4 + l4)*8 + e;                 // stored slot
    int k  = layer ? colmap(ks) : ks;           // actual k this slot must hold
    float v = (l15 == 0) ? wa[0][k] : ((l15 == 1) ? wa[1][k] : 0.f);
    unsigned short h = bf16_rn(v);
    hh[e] = h;
    ll[e] = bf16_rn(v - __uint_as_float(((unsigned)h) << 16));
  }
  #pragma unroll
  for (int e = 0; e < 8; ++e){ Whfx[t*8 + e] = hh[e]; Wlfx[t*8 + e] = ll[e]; }
}

__global__ __launch_bounds__(256) void bucket_csr_kernel(const unsigned int* __restrict__ ebuf,
    const int* __restrict__ bcur, int2* __restrict__ rowrange, int* __restrict__ colb,
    int n, int nbuck){
  __shared__ int c[512];
  __shared__ int ps[256];
  int b = blockIdx.x;
  int t = threadIdx.x;
  int base = b * BCAP;
  int end  = bcur[b];
  c[t] = 0; c[t+256] = 0;
  __syncthreads();
  for (int i = base + t; i < end; i += 256)
    atomicAdd(&c[ebuf[i] & (BSZ-1)], 1);
  __syncthreads();
  int a0 = c[2*t], a1 = c[2*t+1];
  int pair = a0 + a1;
  ps[t] = pair;
  __syncthreads();
  #pragma unroll
  for (int d = 1; d < 256; d <<= 1){
    int add = (t >= d) ? ps[t-d] : 0;
    __syncthreads();
    ps[t] += add;
    __syncthreads();
  }
  int excl = ps[t] - pair;
  __syncthreads();
  int lo = b << BSH;
  int g0 = lo + 2*t, g1 = g0 + 1;
  if (g0 < n) rowrange[g0] = make_int2(base + excl,      base + excl + a0);
  if (g1 < n) rowrange[g1] = make_int2(base + excl + a0, base + excl + a0 + a1);
  c[2*t]   = excl;
  c[2*t+1] = excl + a0;
  __syncthreads();
  for (int i = base + t; i < end; i += 256){
    unsigned int p = ebuf[i];
    int dlo = p & (BSZ-1);
    int pos = base + atomicAdd(&c[dlo], 1);
    colb[pos] = (int)(p >> BSH);
  }
}

// ---------------- FAT kernel: bucket_scatter (blocks 0..sc_blocks-1) + gemm1 fp32 ----------------
__global__ __launch_bounds__(256) void gemm1_scatter_kernel(const float* __restrict__ X,
    const unsigned short* __restrict__ Whf, const unsigned short* __restrict__ Wlf,
    const unsigned short* __restrict__ Whfx, const unsigned short* __restrict__ Wlfx,
    unsigned short* __restrict__ Hb, float* __restrict__ ALs, float* __restrict__ ALd,
    unsigned int* __restrict__ mx, int n, int sc_blocks,
    const int* __restrict__ src, const int* __restrict__ dst, int E,
    int* __restrict__ bcur, unsigned int* __restrict__ ebuf, int nbuck)
{
  __shared__ unsigned short Xh[128*128];   // 32 KB (scatter overlays h/cb on it)
  __shared__ float redS[4], redD[4];
  int tid  = threadIdx.x;

  if (blockIdx.x < sc_blocks){
    int* h  = (int*)Xh;
    int* cb = h + 256;
    int base = blockIdx.x * SC_CHUNK;
    int end = base + SC_CHUNK; if (end > E) end = E;
    h[tid] = 0;
    __syncthreads();
    for (int e = base + tid; e < end; e += 256)
      atomicAdd(&h[dst[e] >> BSH], 1);
    __syncthreads();
    if (tid < nbuck){
      cb[tid] = h[tid] ? atomicAdd(&bcur[tid], h[tid]) : 0;
      h[tid] = 0;
    }
    __syncthreads();
    for (int e = base + tid; e < end; e += 256){
      int d = dst[e];
      int b = d >> BSH;
      int lpos = atomicAdd(&h[b], 1);
      ebuf[cb[b] + lpos] = ((unsigned int)src[e] << BSH) | (unsigned int)(d & (BSZ-1));
    }
    return;
  }

  int lane = tid & 63;
  int wave = tid >> 6;
  int row0 = (blockIdx.x - sc_blocks) * 128;
  int c4   = tid & 31;

  #pragma unroll 4
  for (int it = 0; it < 16; ++it){
    int f  = it*256 + tid;      // 0..4095
    int r  = f >> 5;            // 0..127
    float4 v = make_float4(0.f,0.f,0.f,0.f);
    int gr = row0 + r;
    if (gr < n) v = ((const float4*)(X + (size_t)gr*D))[c4];
    unsigned short h0 = bf16_rn(v.x);
    unsigned short h1 = bf16_rn(v.y);
    unsigned short h2 = bf16_rn(v.z);
    unsigned short h3 = bf16_rn(v.w);
    int g   = (c4 >> 1) ^ (r & 7);
    int idx = r*128 + (g << 3) + ((c4 & 1) << 2);
    *(uint2*)&Xh[idx] = make_uint2((unsigned)h0 | ((unsigned)h1<<16),
                                   (unsigned)h2 | ((unsigned)h3<<16));
  }
  __syncthreads();

  int l15 = lane & 15;
  int l4  = lane >> 4;

  f32x4 acc[2][8];
  f32x4 acc2[2];
  #pragma unroll
  for (int rf = 0; rf < 2; ++rf){
    #pragma unroll
    for (int cf = 0; cf < 8; ++cf)
      acc[rf][cf] = (f32x4){0.f, 0.f, 0.f, 0.f};
    acc2[rf] = (f32x4){0.f, 0.f, 0.f, 0.f};
  }

  #pragma unroll
  for (int kc = 0; kc < 4; ++kc){
    int g = kc*4 + l4;
    bf16x8 ah[2];
    #pragma unroll
    for (int rf = 0; rf < 2; ++rf){
      int r   = wave*32 + rf*16 + l15;
      int idx = r*128 + ((g ^ (r & 7)) << 3);
      ah[rf] = *(const bf16x8*)&Xh[idx];
    }
    #pragma unroll
    for (int cf = 0; cf < 8; ++cf){
      int foff = ((kc*8 + cf) << 9) + (lane << 3);
      bf16x8 bh = *(const bf16x8*)&Whf[foff];
      bf16x8 bl = *(const bf16x8*)&Wlf[foff];
      #pragma unroll
      for (int rf = 0; rf < 2; ++rf){
        acc[rf][cf] = __builtin_amdgcn_mfma_f32_16x16x32_bf16(ah[rf], bh, acc[rf][cf], 0, 0, 0);
        acc[rf][cf] = __builtin_amdgcn_mfma_f32_16x16x32_bf16(ah[rf], bl, acc[rf][cf], 0, 0, 0);
      }
    }
    {
      int foffx = ((kc << 6) + lane) << 3;
      bf16x8 bhx = *(const bf16x8*)&Whfx[foffx];
      bf16x8 blx = *(const bf16x8*)&Wlfx[foffx];
      #pragma unroll
      for (int rf = 0; rf < 2; ++rf){
        acc2[rf] = __builtin_amdgcn_mfma_f32_16x16x32_bf16(ah[rf], bhx, acc2[rf], 0, 0, 0);
        acc2[rf] = __builtin_amdgcn_mfma_f32_16x16x32_bf16(ah[rf], blx, acc2[rf], 0, 0, 0);
      }
    }
  }

  float ms = -3e38f, md = -3e38f;
  #pragma unroll
  for (int rf = 0; rf < 2; ++rf){
    #pragma unroll
    for (int reg = 0; reg < 4; ++reg){
      int gr = row0 + wave*32 + rf*16 + l4*4 + reg;   // C/D: row=(lane>>4)*4+reg
      if (gr < n){
        unsigned int p0 = (unsigned)bf16_rn(acc[rf][0][reg]) | ((unsigned)bf16_rn(acc[rf][1][reg]) << 16);
        unsigned int p1 = (unsigned)bf16_rn(acc[rf][2][reg]) | ((unsigned)bf16_rn(acc[rf][3][reg]) << 16);
        unsigned int p2 = (unsigned)bf16_rn(acc[rf][4][reg]) | ((unsigned)bf16_rn(acc[rf][5][reg]) << 16);
        unsigned int p3 = (unsigned)bf16_rn(acc[rf][6][reg]) | ((unsigned)bf16_rn(acc[rf][7][reg]) << 16);
        ((uint4*)(Hb + (size_t)gr*D))[l15] = make_uint4(p0, p1, p2, p3);
        if (l15 == 0){      ALs[gr] = acc2[rf][reg]; ms = fmaxf(ms, acc2[rf][reg]); }
        else if (l15 == 1){ ALd[gr] = acc2[rf][reg]; md = fmaxf(md, acc2[rf][reg]); }
      }
    }
  }
  #pragma unroll
  for (int off = 32; off >= 1; off >>= 1){
    ms = fmaxf(ms, __shfl_xor(ms, off));
    md = fmaxf(md, __shfl_xor(md, off));
  }
  if (lane == 0){ redS[wave] = ms; redD[wave] = md; }
  __syncthreads();
  if (tid == 0){
    float a = fmaxf(fmaxf(redS[0], redS[1]), fmaxf(redS[2], redS[3]));
    float b = fmaxf(fmaxf(redD[0], redD[1]), fmaxf(redD[2], redD[3]));
    atomicMax(&mx[0], enc_f(a));
    atomicMax(&mx[1], enc_f(b));
  }
}

// ---------------- MFMA bf16 GEMM layer 2 (bf16 permuted input), 128-row tile ----------------
__global__ __launch_bounds__(256) void gemm2_kernel(const unsigned short* __restrict__ Xb,
    const unsigned short* __restrict__ Whf, const unsigned short* __restrict__ Wlf,
    const unsigned short* __restrict__ Whfx, const unsigned short* __restrict__ Wlfx,
    unsigned short* __restrict__ Hb, float* __restrict__ ALs, float* __restrict__ ALd,
    unsigned int* __restrict__ mx, int n)
{
  __shared__ unsigned short Xh[128*128];
  __shared__ float redS[4], redD[4];
  int tid  = threadIdx.x;
  int lane = tid & 63;
  int wave = tid >> 6;
  int row0 = blockIdx.x * 128;

  const uint4* X4 = (const uint4*)Xb;
  #pragma unroll
  for (int it = 0; it < 8; ++it){
    int f  = it*256 + tid;      // 0..2047
    int r  = f >> 4;            // 0..127
    int pg = f & 15;            // 16B group within row
    uint4 v = make_uint4(0u,0u,0u,0u);
    int gr = row0 + r;
    if (gr < n) v = X4[(size_t)gr*16 + pg];
    *(uint4*)&Xh[r*128 + ((pg ^ (r & 7)) << 3)] = v;
  }
  __syncthreads();

  int l15 = lane & 15;
  int l4  = lane >> 4;

  f32x4 acc[2][8];
  f32x4 acc2[2];
  #pragma unroll
  for (int rf = 0; rf < 2; ++rf){
    #pragma unroll
    for (int cf = 0; cf < 8; ++cf)
      acc[rf][cf] = (f32x4){0.f, 0.f, 0.f, 0.f};
    acc2[rf] = (f32x4){0.f, 0.f, 0.f, 0.f};
  }

  #pragma unroll
  for (int kc = 0; kc < 4; ++kc){
    int g = kc*4 + l4;
    bf16x8 ah[2];
    #pragma unroll
    for (int rf = 0; rf < 2; ++rf){
      int r   = wave*32 + rf*16 + l15;
      int idx = r*128 + ((g ^ (r & 7)) << 3);
      ah[rf] = *(const bf16x8*)&Xh[idx];
    }
    #pragma unroll
    for (int cf = 0; cf < 8; ++cf){
      int foff = ((kc*8 + cf) << 9) + (lane << 3);
      bf16x8 bh = *(const bf16x8*)&Whf[foff];
      bf16x8 bl = *(const bf16x8*)&Wlf[foff];
      #pragma unroll
      for (int rf = 0; rf < 2; ++rf){
        acc[rf][cf] = __builtin_amdgcn_mfma_f32_16x16x32_bf16(ah[rf], bh, acc[rf][cf], 0, 0, 0);
        acc[rf][cf] = __builtin_amdgcn_mfma_f32_16x16x32_bf16(ah[rf], bl, acc[rf][cf], 0, 0, 0);
      }
    }
    {
      int foffx = ((kc << 6) + lane) << 3;
      bf16x8 bhx = *(const bf16x8*)&Whfx[foffx];
      bf16x8 blx = *(const bf16x8*)&Wlfx[foffx];
      #pragma unroll
      for (int rf = 0; rf < 2; ++rf){
        acc2[rf] = __builtin_amdgcn_mfma_f32_16x16x32_bf16(ah[rf], bhx, acc2[rf], 0, 0, 0);
        acc2[rf] = __builtin_amdgcn_mfma_f32_16x16x32_bf16(ah[rf], blx, acc2[rf], 0, 0, 0);
      }
    }
  }

  float ms = -3e38f, md = -3e38f;
  #pragma unroll
  for (int rf = 0; rf < 2; ++rf){
    #pragma unroll
    for (int reg = 0; reg < 4; ++reg){
      int gr = row0 + wave*32 + rf*16 + l4*4 + reg;
      if (gr < n){
        unsigned int p0 = (unsigned)bf16_rn(acc[rf][0][reg]) | ((unsigned)bf16_rn(acc[rf][1][reg]) << 16);
        unsigned int p1 = (unsigned)bf16_rn(acc[rf][2][reg]) | ((unsigned)bf16_rn(acc[rf][3][reg]) << 16);
        unsigned int p2 = (unsigned)bf16_rn(acc[rf][4][reg]) | ((unsigned)bf16_rn(acc[rf][5][reg]) << 16);
        unsigned int p3 = (unsigned)bf16_rn(acc[rf][6][reg]) | ((unsigned)bf16_rn(acc[rf][7][reg]) << 16);
        ((uint4*)(Hb + (size_t)gr*D))[l15] = make_uint4(p0, p1, p2, p3);
        if (l15 == 0){      ALs[gr] = acc2[rf][reg]; ms = fmaxf(ms, acc2[rf][reg]); }
        else if (l15 == 1){ ALd[gr] = acc2[rf][reg]; md = fmaxf(md, acc2[rf][reg]); }
      }
    }
  }
  #pragma unroll
  for (int off = 32; off >= 1; off >>= 1){
    ms = fmaxf(ms, __shfl_xor(ms, off));
    md = fmaxf(md, __shfl_xor(md, off));
  }
  if (lane == 0){ redS[wave] = ms; redD[wave] = md; }
  __syncthreads();
  if (tid == 0){
    float a = fmaxf(fmaxf(redS[0], redS[1]), fmaxf(redS[2], redS[3]));
    float b = fmaxf(fmaxf(redD[0], redD[1]), fmaxf(redD[2], redD[3]));
    atomicMax(&mx[0], enc_f(a));
    atomicMax(&mx[1], enc_f(b));
  }
}

// ---------------- fused softmax + weighted gather aggregation ----------------
template<bool BF16OUT>
__global__ __launch_bounds__(256) void agg_kernel(const unsigned short* __restrict__ Hb,
    const float* __restrict__ ALs, const float* __restrict__ ALd,
    const unsigned int* __restrict__ mx,
    const int2* __restrict__ rowrange, const int* __restrict__ colb,
    const float* __restrict__ bias, void* __restrict__ outv, int n)
{
  __shared__ unsigned int sArr[256];
  __shared__ float wArr[256];
  int gtid = blockIdx.x*blockDim.x + threadIdx.x;
  int node = gtid >> 6;
  int lane = threadIdx.x & 63;
  int wbase = threadIdx.x & 192;
  if (node >= n) return;

  float M = lrelu(dec_f(mx[0]) + dec_f(mx[1]));

  int2 rr = rowrange[node];
  int beg = rr.x, end = rr.y;
  float ald = ALd[node];
  float ws = __expf(lrelu(ALs[node] + ald) - M);

  const unsigned int* H2 = (const unsigned int*)Hb;
  unsigned int us = H2[(unsigned)(node*64 + lane)];
  float2 acc; acc.x = ws * bf16_lo_f(us); acc.y = ws * bf16_hi_f(us);
  float zl = 0.f;

  for (int c = beg; c < end; c += 64){
    int j = c + lane;
    bool valid = j < end;
    int s_l = valid ? colb[j] : 0;
    float w_l = valid ? __expf(lrelu(ALs[s_l] + ald) - M) : 0.f;
    zl += w_l;

    sArr[threadIdx.x] = (unsigned)s_l;
    wArr[threadIdx.x] = w_l;

    int cnt = end - c; if (cnt > 64) cnt = 64;
    int q = 0;
    for (; q + 8 <= cnt; q += 8){
      unsigned int ss[8]; float ww[8]; unsigned int u[8];
      #pragma unroll
      for (int p = 0; p < 8; ++p){ ss[p] = sArr[wbase + q + p]; ww[p] = wArr[wbase + q + p]; }
      #pragma unroll
      for (int p = 0; p < 8; ++p) u[p] = H2[(unsigned)(ss[p]*64u + lane)];
      #pragma unroll
      for (int p = 0; p < 8; ++p){
        acc.x += ww[p]*bf16_lo_f(u[p]);
        acc.y += ww[p]*bf16_hi_f(u[p]);
      }
    }
    for (; q < cnt; ++q){
      unsigned int u = H2[(unsigned)(sArr[wbase + q]*64u + lane)];
      float w = wArr[wbase + q];
      acc.x += w*bf16_lo_f(u); acc.y += w*bf16_hi_f(u);
    }
  }

  #pragma unroll
  for (int off = 32; off >= 1; off >>= 1) zl += __shfl_xor(zl, off);
  float zi = 1.f / (zl + ws);
  acc.x *= zi; acc.y *= zi;

  if constexpr (BF16OUT){
    float2 bp = ((const float2*)bias)[lane];
    unsigned int w = (unsigned)bf16_rn(acc.x + bp.x) | ((unsigned)bf16_rn(acc.y + bp.y) << 16);
    ((unsigned int*)outv)[(unsigned)(node*64 + lane)] = w;
  } else {
    int q0 = (lane >> 4) + ((lane & 7) << 3);
    int q1 = q0 + 4;
    int hsel = (lane >> 3) & 1;
    float x0 = __shfl(acc.x, q0), y0 = __shfl(acc.y, q0);
    float x1 = __shfl(acc.x, q1), y1 = __shfl(acc.y, q1);
    float v0 = hsel ? y0 : x0;
    float v1 = hsel ? y1 : x1;
    float2 b2 = ((const float2*)bias)[lane];
    ((float2*)outv)[(size_t)node*64 + lane] = make_float2(v0 + b2.x, v1 + b2.y);
  }
}

// ---------------- launch ----------------
extern "C" void kernel_launch(void* const* d_in, const int* in_sizes, int n_in,
                              void* d_out, int out_size, void* d_ws, size_t ws_size,
                              hipStream_t stream)
{
  const float* x   = (const float*)d_in[0];
  const int*   ei  = (const int*)  d_in[1];
  const float* W1  = (const float*)d_in[2];
  const float* as1 = (const float*)d_in[3];
  const float* ad1 = (const float*)d_in[4];
  const float* b1  = (const float*)d_in[5];
  const float* W2  = (const float*)d_in[6];
  const float* as2 = (const float*)d_in[7];
  const float* ad2 = (const float*)d_in[8];
  const float* b2  = (const float*)d_in[9];

  int n = in_sizes[0] / D;
  int E = in_sizes[1] / 2;
  const int* src = ei;
  const int* dst = ei + E;
  int nbuck = (n + BSZ - 1) >> BSH;

  char* base = (char*)d_ws;
  size_t off = 0;
  auto alloc = [&](size_t bytes) -> char* {
    char* p = base + off;
    off = (off + bytes + 255) & ~(size_t)255;
    return p;
  };
  unsigned short* hb  = (unsigned short*)alloc((size_t)n*D*2);
  unsigned short* hb2 = (unsigned short*)alloc((size_t)n*D*2);
  float* als    = (float*)alloc((size_t)n*4);
  float* ald    = (float*)alloc((size_t)n*4);
  int2* rowrange = (int2*)alloc((size_t)n*8);
  int* bcur     = (int*)alloc(256*4);
  unsigned int* mx = (unsigned int*)alloc(4*4);
  float* bias_perm1 = (float*)alloc(128*4);
  unsigned short* whf1 = (unsigned short*)alloc(16384*2);
  unsigned short* wlf1 = (unsigned short*)alloc(16384*2);
  unsigned short* whf2 = (unsigned short*)alloc(16384*2);
  unsigned short* wlf2 = (unsigned short*)alloc(16384*2);
  unsigned short* whfx1 = (unsigned short*)alloc(2048*2);
  unsigned short* wlfx1 = (unsigned short*)alloc(2048*2);
  unsigned short* whfx2 = (unsigned short*)alloc(2048*2);
  unsigned short* wlfx2 = (unsigned short*)alloc(2048*2);
  unsigned int* ebuf = (unsigned int*)alloc((size_t)nbuck*BCAP*4);
  int* colb = (int*)alloc((size_t)nbuck*BCAP*4);

  float* out = (float*)d_out;

  int sc_blocks = (E + SC_CHUNK - 1) / SC_CHUNK;
  int ntiles = (n + 127)/128;
  int aggblocks = (int)(((size_t)n*64 + 255)/256);

  // 1: prep (wsplit + wafrag + inits)
  prep_kernel<<<130, 256, 0, stream>>>(W1, W2, as1, ad1, as2, ad2, b1,
                                       whf1, wlf1, whf2, wlf2,
                                       whfx1, wlfx1, whfx2, wlfx2,
                                       bias_perm1, mx, bcur, nbuck);
  // 2: fat — scatter (first sc_blocks) + gemm1
  gemm1_scatter_kernel<<<sc_blocks + ntiles, 256, 0, stream>>>(
      x, whf1, wlf1, whfx1, wlfx1, hb, als, ald, mx, n, sc_blocks,
      src, dst, E, bcur, ebuf, nbuck);
  // 3: csr finish
  bucket_csr_kernel<<<nbuck, 256, 0, stream>>>(ebuf, bcur, rowrange, colb, n, nbuck);
  // 4-6: agg1 -> gemm2 -> agg2
  agg_kernel<true>  <<<aggblocks, 256, 0, stream>>>(hb, als, ald, mx,   rowrange, colb, bias_perm1, hb2, n);
  gemm2_kernel      <<<ntiles, 256, 0, stream>>>(hb2, whf2, wlf2, whfx2, wlfx2, hb, als, ald, mx+2, n);
  agg_kernel<false> <<<aggblocks, 256, 0, stream>>>(hb, als, ald, mx+2, rowrange, colb, b2, out, n);
}

// Round 17
// 256.805 us; speedup vs baseline: 1.2098x; 1.0306x over previous
//
#include <hip/hip_runtime.h>
#include <hip/hip_bf16.h>
#include <math.h>

#define D 128
#define LRELU_SLOPE 0.2f
#define BSH 9
#define BSZ 512
#define BCAP 10240
#define SC_CHUNK 2048   // 784 scatter blocks x 256 threads = 200K scatter threads

typedef __attribute__((ext_vector_type(8))) short bf16x8;
typedef __attribute__((ext_vector_type(4))) float f32x4;

__device__ __forceinline__ float lrelu(float x){ return x > 0.f ? x : LRELU_SLOPE * x; }

__device__ __forceinline__ unsigned short bf16_rn(float x){
  unsigned int u = __float_as_uint(x);
  return (unsigned short)((u + 0x7FFFu + ((u >> 16) & 1u)) >> 16);
}
__device__ __forceinline__ float bf16_lo_f(unsigned int u){ return __uint_as_float(u << 16); }
__device__ __forceinline__ float bf16_hi_f(unsigned int u){ return __uint_as_float(u & 0xFFFF0000u); }

__device__ __forceinline__ unsigned int enc_f(float f){
  unsigned int u = __float_as_uint(f);
  return (u & 0x80000000u) ? ~u : (u | 0x80000000u);
}
__device__ __forceinline__ float dec_f(unsigned int e){
  return __uint_as_float((e & 0x80000000u) ? (e & 0x7FFFFFFFu) : ~e);
}

// permuted position p -> actual column
__device__ __forceinline__ int colmap(int p){ return ((p & 7) << 4) + (p >> 3); }

// ---------------- merged prep: W pre-split (blocks 0..127) + wafrag (blocks 128..129) ----------------
__global__ __launch_bounds__(256) void prep_kernel(const float* __restrict__ W1,
    const float* __restrict__ W2,
    const float* __restrict__ as1, const float* __restrict__ ad1,
    const float* __restrict__ as2, const float* __restrict__ ad2,
    const float* __restrict__ b1,
    unsigned short* __restrict__ Whf1, unsigned short* __restrict__ Wlf1,
    unsigned short* __restrict__ Whf2, unsigned short* __restrict__ Wlf2,
    unsigned short* __restrict__ Whfx1, unsigned short* __restrict__ Wlfx1,
    unsigned short* __restrict__ Whfx2, unsigned short* __restrict__ Wlfx2,
    float* __restrict__ bias_perm1,
    unsigned int* __restrict__ mx, int* __restrict__ bcur, int nbuck)
{
  __shared__ float wa[2][128];
  int blk = blockIdx.x;
  if (blk < 128){
    bool layer2 = (blk >= 64);
    const float* W = layer2 ? W2 : W1;
    unsigned short* Whf = layer2 ? Whf2 : Whf1;
    unsigned short* Wlf = layer2 ? Wlf2 : Wlf1;
    int t = (blk & 63)*256 + threadIdx.x;   // 0..16383
    int k  = t >> 7;
    int nn = t & 127;
    float w = W[t];
    unsigned short h = bf16_rn(w);
    float whf = __uint_as_float(((unsigned int)h) << 16);
    unsigned short l = bf16_rn(w - whf);
    int ks = layer2 ? (((k & 15) << 3) + (k >> 4)) : k;   // col(ks) == k
    int kc = ks >> 5, l4 = (ks >> 3) & 3, e = ks & 7;
    int cf = nn >> 4, l15 = nn & 15;
    int idx = ((kc*8 + cf)*64 + l4*16 + l15)*8 + e;
    Whf[idx] = h; Wlf[idx] = l;
    return;
  }
  int layer = blk - 128;
  const float* W  = layer ? W2 : W1;
  const float* as = layer ? as2 : as1;
  const float* ad = layer ? ad2 : ad1;
  unsigned short* Whfx = layer ? Whfx2 : Whfx1;
  unsigned short* Wlfx = layer ? Wlfx2 : Wlfx1;
  int t = threadIdx.x;
  if (t < 2) mx[layer*2 + t] = 0u;
  if (layer == 0 && t < nbuck) bcur[t] = t * BCAP;
  if (layer == 0 && t < 128) bias_perm1[t] = b1[colmap(t)];

  int row = t & 127;
  const float* a = (t >> 7) ? ad : as;
  float s = 0.f;
  #pragma unroll 8
  for (int c = 0; c < 128; c += 4){
    float4 wv = *(const float4*)&W[row*128 + c];
    s += wv.x*a[c] + wv.y*a[c+1] + wv.z*a[c+2] + wv.w*a[c+3];
  }
  wa[t >> 7][row] = s;
  __syncthreads();

  int kc = t >> 6, lane = t & 63;
  int l15 = lane & 15, l4 = lane >> 4;
  unsigned short hh[8], ll[8];
  #pragma unroll
  for (int e = 0; e < 8; ++e){
    int ks = (kc*4 + l4)*8 + e;                 // stored slot
    int k  = layer ? colmap(ks) : ks;           // actual k this slot must hold
    float v = (l15 == 0) ? wa[0][k] : ((l15 == 1) ? wa[1][k] : 0.f);
    unsigned short h = bf16_rn(v);
    hh[e] = h;
    ll[e] = bf16_rn(v - __uint_as_float(((unsigned)h) << 16));
  }
  #pragma unroll
  for (int e = 0; e < 8; ++e){ Whfx[t*8 + e] = hh[e]; Wlfx[t*8 + e] = ll[e]; }
}

__global__ __launch_bounds__(256) void bucket_csr_kernel(const unsigned int* __restrict__ ebuf,
    const int* __restrict__ bcur, int2* __restrict__ rowrange, int* __restrict__ colb,
    int n, int nbuck){
  __shared__ int c[512];
  __shared__ int ps[256];
  int b = blockIdx.x;
  int t = threadIdx.x;
  int base = b * BCAP;
  int end  = bcur[b];
  c[t] = 0; c[t+256] = 0;
  __syncthreads();
  for (int i = base + t; i < end; i += 256)
    atomicAdd(&c[ebuf[i] & (BSZ-1)], 1);
  __syncthreads();
  int a0 = c[2*t], a1 = c[2*t+1];
  int pair = a0 + a1;
  ps[t] = pair;
  __syncthreads();
  #pragma unroll
  for (int d = 1; d < 256; d <<= 1){
    int add = (t >= d) ? ps[t-d] : 0;
    __syncthreads();
    ps[t] += add;
    __syncthreads();
  }
  int excl = ps[t] - pair;
  __syncthreads();
  int lo = b << BSH;
  int g0 = lo + 2*t, g1 = g0 + 1;
  if (g0 < n) rowrange[g0] = make_int2(base + excl,      base + excl + a0);
  if (g1 < n) rowrange[g1] = make_int2(base + excl + a0, base + excl + a0 + a1);
  c[2*t]   = excl;
  c[2*t+1] = excl + a0;
  __syncthreads();
  for (int i = base + t; i < end; i += 256){
    unsigned int p = ebuf[i];
    int dlo = p & (BSZ-1);
    int pos = base + atomicAdd(&c[dlo], 1);
    colb[pos] = (int)(p >> BSH);
  }
}

// ---------------- FAT kernel: bucket_scatter (blocks 0..sc_blocks-1) + gemm1 fp32 ----------------
__global__ __launch_bounds__(256) void gemm1_scatter_kernel(const float* __restrict__ X,
    const unsigned short* __restrict__ Whf, const unsigned short* __restrict__ Wlf,
    const unsigned short* __restrict__ Whfx, const unsigned short* __restrict__ Wlfx,
    unsigned short* __restrict__ Hb, float* __restrict__ ALs, float* __restrict__ ALd,
    unsigned int* __restrict__ mx, int n, int sc_blocks,
    const int* __restrict__ src, const int* __restrict__ dst, int E,
    int* __restrict__ bcur, unsigned int* __restrict__ ebuf, int nbuck)
{
  __shared__ unsigned short Xh[128*128];   // 32 KB (scatter overlays h/cb on it)
  __shared__ float redS[4], redD[4];
  int tid  = threadIdx.x;

  if (blockIdx.x < sc_blocks){
    int* h  = (int*)Xh;
    int* cb = h + 256;
    int base = blockIdx.x * SC_CHUNK;
    int end = base + SC_CHUNK; if (end > E) end = E;
    h[tid] = 0;
    __syncthreads();
    for (int e = base + tid; e < end; e += 256)
      atomicAdd(&h[dst[e] >> BSH], 1);
    __syncthreads();
    if (tid < nbuck){
      cb[tid] = h[tid] ? atomicAdd(&bcur[tid], h[tid]) : 0;
      h[tid] = 0;
    }
    __syncthreads();
    for (int e = base + tid; e < end; e += 256){
      int d = dst[e];
      int b = d >> BSH;
      int lpos = atomicAdd(&h[b], 1);
      ebuf[cb[b] + lpos] = ((unsigned int)src[e] << BSH) | (unsigned int)(d & (BSZ-1));
    }
    return;
  }

  int lane = tid & 63;
  int wave = tid >> 6;
  int row0 = (blockIdx.x - sc_blocks) * 128;
  int c4   = tid & 31;

  // staging: two batches of 8 outstanding float4 loads, then convert+store
  #pragma unroll
  for (int half = 0; half < 2; ++half){
    float4 v[8];
    #pragma unroll
    for (int i = 0; i < 8; ++i){
      int it = half*8 + i;
      int f  = it*256 + tid;      // 0..4095
      int r  = f >> 5;            // 0..127
      int gr = row0 + r;
      v[i] = make_float4(0.f,0.f,0.f,0.f);
      if (gr < n) v[i] = ((const float4*)(X + (size_t)gr*D))[c4];
    }
    #pragma unroll
    for (int i = 0; i < 8; ++i){
      int it = half*8 + i;
      int f  = it*256 + tid;
      int r  = f >> 5;
      unsigned short h0 = bf16_rn(v[i].x);
      unsigned short h1 = bf16_rn(v[i].y);
      unsigned short h2 = bf16_rn(v[i].z);
      unsigned short h3 = bf16_rn(v[i].w);
      int g   = (c4 >> 1) ^ (r & 7);
      int idx = r*128 + (g << 3) + ((c4 & 1) << 2);
      *(uint2*)&Xh[idx] = make_uint2((unsigned)h0 | ((unsigned)h1<<16),
                                     (unsigned)h2 | ((unsigned)h3<<16));
    }
  }
  __syncthreads();

  int l15 = lane & 15;
  int l4  = lane >> 4;

  f32x4 acc[2][8];
  f32x4 acc2[2];
  #pragma unroll
  for (int rf = 0; rf < 2; ++rf){
    #pragma unroll
    for (int cf = 0; cf < 8; ++cf)
      acc[rf][cf] = (f32x4){0.f, 0.f, 0.f, 0.f};
    acc2[rf] = (f32x4){0.f, 0.f, 0.f, 0.f};
  }

  #pragma unroll
  for (int kc = 0; kc < 4; ++kc){
    int g = kc*4 + l4;
    bf16x8 ah[2];
    #pragma unroll
    for (int rf = 0; rf < 2; ++rf){
      int r   = wave*32 + rf*16 + l15;
      int idx = r*128 + ((g ^ (r & 7)) << 3);
      ah[rf] = *(const bf16x8*)&Xh[idx];
    }
    #pragma unroll
    for (int cf = 0; cf < 8; ++cf){
      int foff = ((kc*8 + cf) << 9) + (lane << 3);
      bf16x8 bh = *(const bf16x8*)&Whf[foff];
      bf16x8 bl = *(const bf16x8*)&Wlf[foff];
      #pragma unroll
      for (int rf = 0; rf < 2; ++rf){
        acc[rf][cf] = __builtin_amdgcn_mfma_f32_16x16x32_bf16(ah[rf], bh, acc[rf][cf], 0, 0, 0);
        acc[rf][cf] = __builtin_amdgcn_mfma_f32_16x16x32_bf16(ah[rf], bl, acc[rf][cf], 0, 0, 0);
      }
    }
    {
      int foffx = ((kc << 6) + lane) << 3;
      bf16x8 bhx = *(const bf16x8*)&Whfx[foffx];
      bf16x8 blx = *(const bf16x8*)&Wlfx[foffx];
      #pragma unroll
      for (int rf = 0; rf < 2; ++rf){
        acc2[rf] = __builtin_amdgcn_mfma_f32_16x16x32_bf16(ah[rf], bhx, acc2[rf], 0, 0, 0);
        acc2[rf] = __builtin_amdgcn_mfma_f32_16x16x32_bf16(ah[rf], blx, acc2[rf], 0, 0, 0);
      }
    }
  }

  float ms = -3e38f, md = -3e38f;
  #pragma unroll
  for (int rf = 0; rf < 2; ++rf){
    #pragma unroll
    for (int reg = 0; reg < 4; ++reg){
      int gr = row0 + wave*32 + rf*16 + l4*4 + reg;   // C/D: row=(lane>>4)*4+reg
      if (gr < n){
        unsigned int p0 = (unsigned)bf16_rn(acc[rf][0][reg]) | ((unsigned)bf16_rn(acc[rf][1][reg]) << 16);
        unsigned int p1 = (unsigned)bf16_rn(acc[rf][2][reg]) | ((unsigned)bf16_rn(acc[rf][3][reg]) << 16);
        unsigned int p2 = (unsigned)bf16_rn(acc[rf][4][reg]) | ((unsigned)bf16_rn(acc[rf][5][reg]) << 16);
        unsigned int p3 = (unsigned)bf16_rn(acc[rf][6][reg]) | ((unsigned)bf16_rn(acc[rf][7][reg]) << 16);
        ((uint4*)(Hb + (size_t)gr*D))[l15] = make_uint4(p0, p1, p2, p3);
        if (l15 == 0){      ALs[gr] = acc2[rf][reg]; ms = fmaxf(ms, acc2[rf][reg]); }
        else if (l15 == 1){ ALd[gr] = acc2[rf][reg]; md = fmaxf(md, acc2[rf][reg]); }
      }
    }
  }
  #pragma unroll
  for (int off = 32; off >= 1; off >>= 1){
    ms = fmaxf(ms, __shfl_xor(ms, off));
    md = fmaxf(md, __shfl_xor(md, off));
  }
  if (lane == 0){ redS[wave] = ms; redD[wave] = md; }
  __syncthreads();
  if (tid == 0){
    float a = fmaxf(fmaxf(redS[0], redS[1]), fmaxf(redS[2], redS[3]));
    float b = fmaxf(fmaxf(redD[0], redD[1]), fmaxf(redD[2], redD[3]));
    atomicMax(&mx[0], enc_f(a));
    atomicMax(&mx[1], enc_f(b));
  }
}

// ---------------- MFMA bf16 GEMM layer 2 (bf16 permuted input), 128-row tile ----------------
__global__ __launch_bounds__(256) void gemm2_kernel(const unsigned short* __restrict__ Xb,
    const unsigned short* __restrict__ Whf, const unsigned short* __restrict__ Wlf,
    const unsigned short* __restrict__ Whfx, const unsigned short* __restrict__ Wlfx,
    unsigned short* __restrict__ Hb, float* __restrict__ ALs, float* __restrict__ ALd,
    unsigned int* __restrict__ mx, int n)
{
  __shared__ unsigned short Xh[128*128];
  __shared__ float redS[4], redD[4];
  int tid  = threadIdx.x;
  int lane = tid & 63;
  int wave = tid >> 6;
  int row0 = blockIdx.x * 128;

  const uint4* X4 = (const uint4*)Xb;
  {
    uint4 v[8];
    #pragma unroll
    for (int it = 0; it < 8; ++it){
      int f  = it*256 + tid;      // 0..2047
      int r  = f >> 4;            // 0..127
      int pg = f & 15;            // 16B group within row
      int gr = row0 + r;
      v[it] = make_uint4(0u,0u,0u,0u);
      if (gr < n) v[it] = X4[(size_t)gr*16 + pg];
    }
    #pragma unroll
    for (int it = 0; it < 8; ++it){
      int f  = it*256 + tid;
      int r  = f >> 4;
      int pg = f & 15;
      *(uint4*)&Xh[r*128 + ((pg ^ (r & 7)) << 3)] = v[it];
    }
  }
  __syncthreads();

  int l15 = lane & 15;
  int l4  = lane >> 4;

  f32x4 acc[2][8];
  f32x4 acc2[2];
  #pragma unroll
  for (int rf = 0; rf < 2; ++rf){
    #pragma unroll
    for (int cf = 0; cf < 8; ++cf)
      acc[rf][cf] = (f32x4){0.f, 0.f, 0.f, 0.f};
    acc2[rf] = (f32x4){0.f, 0.f, 0.f, 0.f};
  }

  #pragma unroll
  for (int kc = 0; kc < 4; ++kc){
    int g = kc*4 + l4;
    bf16x8 ah[2];
    #pragma unroll
    for (int rf = 0; rf < 2; ++rf){
      int r   = wave*32 + rf*16 + l15;
      int idx = r*128 + ((g ^ (r & 7)) << 3);
      ah[rf] = *(const bf16x8*)&Xh[idx];
    }
    #pragma unroll
    for (int cf = 0; cf < 8; ++cf){
      int foff = ((kc*8 + cf) << 9) + (lane << 3);
      bf16x8 bh = *(const bf16x8*)&Whf[foff];
      bf16x8 bl = *(const bf16x8*)&Wlf[foff];
      #pragma unroll
      for (int rf = 0; rf < 2; ++rf){
        acc[rf][cf] = __builtin_amdgcn_mfma_f32_16x16x32_bf16(ah[rf], bh, acc[rf][cf], 0, 0, 0);
        acc[rf][cf] = __builtin_amdgcn_mfma_f32_16x16x32_bf16(ah[rf], bl, acc[rf][cf], 0, 0, 0);
      }
    }
    {
      int foffx = ((kc << 6) + lane) << 3;
      bf16x8 bhx = *(const bf16x8*)&Whfx[foffx];
      bf16x8 blx = *(const bf16x8*)&Wlfx[foffx];
      #pragma unroll
      for (int rf = 0; rf < 2; ++rf){
        acc2[rf] = __builtin_amdgcn_mfma_f32_16x16x32_bf16(ah[rf], bhx, acc2[rf], 0, 0, 0);
        acc2[rf] = __builtin_amdgcn_mfma_f32_16x16x32_bf16(ah[rf], blx, acc2[rf], 0, 0, 0);
      }
    }
  }

  float ms = -3e38f, md = -3e38f;
  #pragma unroll
  for (int rf = 0; rf < 2; ++rf){
    #pragma unroll
    for (int reg = 0; reg < 4; ++reg){
      int gr = row0 + wave*32 + rf*16 + l4*4 + reg;
      if (gr < n){
        unsigned int p0 = (unsigned)bf16_rn(acc[rf][0][reg]) | ((unsigned)bf16_rn(acc[rf][1][reg]) << 16);
        unsigned int p1 = (unsigned)bf16_rn(acc[rf][2][reg]) | ((unsigned)bf16_rn(acc[rf][3][reg]) << 16);
        unsigned int p2 = (unsigned)bf16_rn(acc[rf][4][reg]) | ((unsigned)bf16_rn(acc[rf][5][reg]) << 16);
        unsigned int p3 = (unsigned)bf16_rn(acc[rf][6][reg]) | ((unsigned)bf16_rn(acc[rf][7][reg]) << 16);
        ((uint4*)(Hb + (size_t)gr*D))[l15] = make_uint4(p0, p1, p2, p3);
        if (l15 == 0){      ALs[gr] = acc2[rf][reg]; ms = fmaxf(ms, acc2[rf][reg]); }
        else if (l15 == 1){ ALd[gr] = acc2[rf][reg]; md = fmaxf(md, acc2[rf][reg]); }
      }
    }
  }
  #pragma unroll
  for (int off = 32; off >= 1; off >>= 1){
    ms = fmaxf(ms, __shfl_xor(ms, off));
    md = fmaxf(md, __shfl_xor(md, off));
  }
  if (lane == 0){ redS[wave] = ms; redD[wave] = md; }
  __syncthreads();
  if (tid == 0){
    float a = fmaxf(fmaxf(redS[0], redS[1]), fmaxf(redS[2], redS[3]));
    float b = fmaxf(fmaxf(redD[0], redD[1]), fmaxf(redD[2], redD[3]));
    atomicMax(&mx[0], enc_f(a));
    atomicMax(&mx[1], enc_f(b));
  }
}

// ---------------- fused softmax + weighted gather aggregation ----------------
template<bool BF16OUT>
__global__ __launch_bounds__(256) void agg_kernel(const unsigned short* __restrict__ Hb,
    const float* __restrict__ ALs, const float* __restrict__ ALd,
    const unsigned int* __restrict__ mx,
    const int2* __restrict__ rowrange, const int* __restrict__ colb,
    const float* __restrict__ bias, void* __restrict__ outv, int n)
{
  __shared__ unsigned int sArr[256];
  __shared__ float wArr[256];
  int gtid = blockIdx.x*blockDim.x + threadIdx.x;
  int node = gtid >> 6;
  int lane = threadIdx.x & 63;
  int wbase = threadIdx.x & 192;
  if (node >= n) return;

  float M = lrelu(dec_f(mx[0]) + dec_f(mx[1]));

  int2 rr = rowrange[node];
  int beg = rr.x, end = rr.y;
  float ald = ALd[node];
  float ws = __expf(lrelu(ALs[node] + ald) - M);

  const unsigned int* H2 = (const unsigned int*)Hb;
  unsigned int us = H2[(unsigned)(node*64 + lane)];
  float2 acc; acc.x = ws * bf16_lo_f(us); acc.y = ws * bf16_hi_f(us);
  float zl = 0.f;

  for (int c = beg; c < end; c += 64){
    int j = c + lane;
    bool valid = j < end;
    int s_l = valid ? colb[j] : 0;
    float w_l = valid ? __expf(lrelu(ALs[s_l] + ald) - M) : 0.f;
    zl += w_l;

    sArr[threadIdx.x] = (unsigned)s_l;
    wArr[threadIdx.x] = w_l;

    int cnt = end - c; if (cnt > 64) cnt = 64;
    int q = 0;
    for (; q + 8 <= cnt; q += 8){
      unsigned int ss[8]; float ww[8]; unsigned int u[8];
      #pragma unroll
      for (int p = 0; p < 8; ++p){ ss[p] = sArr[wbase + q + p]; ww[p] = wArr[wbase + q + p]; }
      #pragma unroll
      for (int p = 0; p < 8; ++p) u[p] = H2[(unsigned)(ss[p]*64u + lane)];
      #pragma unroll
      for (int p = 0; p < 8; ++p){
        acc.x += ww[p]*bf16_lo_f(u[p]);
        acc.y += ww[p]*bf16_hi_f(u[p]);
      }
    }
    for (; q < cnt; ++q){
      unsigned int u = H2[(unsigned)(sArr[wbase + q]*64u + lane)];
      float w = wArr[wbase + q];
      acc.x += w*bf16_lo_f(u); acc.y += w*bf16_hi_f(u);
    }
  }

  #pragma unroll
  for (int off = 32; off >= 1; off >>= 1) zl += __shfl_xor(zl, off);
  float zi = 1.f / (zl + ws);
  acc.x *= zi; acc.y *= zi;

  if constexpr (BF16OUT){
    float2 bp = ((const float2*)bias)[lane];
    unsigned int w = (unsigned)bf16_rn(acc.x + bp.x) | ((unsigned)bf16_rn(acc.y + bp.y) << 16);
    ((unsigned int*)outv)[(unsigned)(node*64 + lane)] = w;
  } else {
    int q0 = (lane >> 4) + ((lane & 7) << 3);
    int q1 = q0 + 4;
    int hsel = (lane >> 3) & 1;
    float x0 = __shfl(acc.x, q0), y0 = __shfl(acc.y, q0);
    float x1 = __shfl(acc.x, q1), y1 = __shfl(acc.y, q1);
    float v0 = hsel ? y0 : x0;
    float v1 = hsel ? y1 : x1;
    float2 b2 = ((const float2*)bias)[lane];
    ((float2*)outv)[(size_t)node*64 + lane] = make_float2(v0 + b2.x, v1 + b2.y);
  }
}

// ---------------- launch ----------------
extern "C" void kernel_launch(void* const* d_in, const int* in_sizes, int n_in,
                              void* d_out, int out_size, void* d_ws, size_t ws_size,
                              hipStream_t stream)
{
  const float* x   = (const float*)d_in[0];
  const int*   ei  = (const int*)  d_in[1];
  const float* W1  = (const float*)d_in[2];
  const float* as1 = (const float*)d_in[3];
  const float* ad1 = (const float*)d_in[4];
  const float* b1  = (const float*)d_in[5];
  const float* W2  = (const float*)d_in[6];
  const float* as2 = (const float*)d_in[7];
  const float* ad2 = (const float*)d_in[8];
  const float* b2  = (const float*)d_in[9];

  int n = in_sizes[0] / D;
  int E = in_sizes[1] / 2;
  const int* src = ei;
  const int* dst = ei + E;
  int nbuck = (n + BSZ - 1) >> BSH;

  char* base = (char*)d_ws;
  size_t off = 0;
  auto alloc = [&](size_t bytes) -> char* {
    char* p = base + off;
    off = (off + bytes + 255) & ~(size_t)255;
    return p;
  };
  unsigned short* hb  = (unsigned short*)alloc((size_t)n*D*2);
  unsigned short* hb2 = (unsigned short*)alloc((size_t)n*D*2);
  float* als    = (float*)alloc((size_t)n*4);
  float* ald    = (float*)alloc((size_t)n*4);
  int2* rowrange = (int2*)alloc((size_t)n*8);
  int* bcur     = (int*)alloc(256*4);
  unsigned int* mx = (unsigned int*)alloc(4*4);
  float* bias_perm1 = (float*)alloc(128*4);
  unsigned short* whf1 = (unsigned short*)alloc(16384*2);
  unsigned short* wlf1 = (unsigned short*)alloc(16384*2);
  unsigned short* whf2 = (unsigned short*)alloc(16384*2);
  unsigned short* wlf2 = (unsigned short*)alloc(16384*2);
  unsigned short* whfx1 = (unsigned short*)alloc(2048*2);
  unsigned short* wlfx1 = (unsigned short*)alloc(2048*2);
  unsigned short* whfx2 = (unsigned short*)alloc(2048*2);
  unsigned short* wlfx2 = (unsigned short*)alloc(2048*2);
  unsigned int* ebuf = (unsigned int*)alloc((size_t)nbuck*BCAP*4);
  int* colb = (int*)alloc((size_t)nbuck*BCAP*4);

  float* out = (float*)d_out;

  int sc_blocks = (E + SC_CHUNK - 1) / SC_CHUNK;
  int ntiles = (n + 127)/128;
  int aggblocks = (int)(((size_t)n*64 + 255)/256);

  // 1: prep (wsplit + wafrag + inits)
  prep_kernel<<<130, 256, 0, stream>>>(W1, W2, as1, ad1, as2, ad2, b1,
                                       whf1, wlf1, whf2, wlf2,
                                       whfx1, wlfx1, whfx2, wlfx2,
                                       bias_perm1, mx, bcur, nbuck);
  // 2: fat — scatter (first sc_blocks) + gemm1
  gemm1_scatter_kernel<<<sc_blocks + ntiles, 256, 0, stream>>>(
      x, whf1, wlf1, whfx1, wlfx1, hb, als, ald, mx, n, sc_blocks,
      src, dst, E, bcur, ebuf, nbuck);
  // 3: csr finish
  bucket_csr_kernel<<<nbuck, 256, 0, stream>>>(ebuf, bcur, rowrange, colb, n, nbuck);
  // 4-6: agg1 -> gemm2 -> agg2
  agg_kernel<true>  <<<aggblocks, 256, 0, stream>>>(hb, als, ald, mx,   rowrange, colb, bias_perm1, hb2, n);
  gemm2_kernel      <<<ntiles, 256, 0, stream>>>(hb2, whf2, wlf2, whfx2, wlfx2, hb, als, ald, mx+2, n);
  agg_kernel<false> <<<aggblocks, 256, 0, stream>>>(hb, als, ald, mx+2, rowrange, colb, b2, out, n);
}